// Round 2
// baseline (1212.028 us; speedup 1.0000x reference)
//
#include <hip/hip_runtime.h>
#include <hip/hip_bf16.h>

typedef __hip_bfloat16 bf16;

__device__ __forceinline__ float b2f(bf16 x) { return __bfloat162float(x); }
__device__ __forceinline__ bf16  f2b(float x) { return __float2bfloat16(x); }

constexpr int N_ = 8, C_ = 64, T_ = 256, VQ_ = 90, VK_ = 50, S_ = 4, L_ = 4;
constexpr int Tq_ = T_ - L_;     // 252
constexpr int NL  = L_ + 1;      // 5 lags
constexpr int NCH = 8, TCH = 32; // t-chunking for score partials
constexpr int COLS = T_ * VQ_;   // 23040
constexpr float EPSf = 1e-5f;

// ---------------------------------------------------------------- K0: fold Wq into key side
// Mt[s][cj][ci] = sum_c Wq[s*64+c][ci] * Wk[s*64+c][cj]   (transposed for coalesced reads)
// bM[s][ci]    = sum_c Wq[s*64+c][ci] * bk[s*64+c]
// wb[s][cj]    = sum_c bq[s*64+c]    * Wk[s*64+c][cj]
// cb[s]        = sum_c bq[s*64+c]    * bk[s*64+c]
__global__ __launch_bounds__(64)
void k0_precompute(const float* __restrict__ Wq, const float* __restrict__ bq,
                   const float* __restrict__ Wk, const float* __restrict__ bk,
                   float* __restrict__ Mt, float* __restrict__ bM,
                   float* __restrict__ wb, float* __restrict__ cb) {
    int s  = blockIdx.x >> 6;
    int ci = blockIdx.x & 63;
    int cj = threadIdx.x;
    float m = 0.f;
    for (int c = 0; c < C_; ++c)
        m += Wq[(s * C_ + c) * C_ + ci] * Wk[(s * C_ + c) * C_ + cj];
    Mt[(s * C_ + cj) * C_ + ci] = m;
    if (cj == 0) {
        float v = 0.f;
        for (int c = 0; c < C_; ++c)
            v += Wq[(s * C_ + c) * C_ + ci] * bk[s * C_ + c];
        bM[s * C_ + ci] = v;
    }
    if (ci == 0) {
        float v = 0.f;
        for (int c = 0; c < C_; ++c)
            v += bq[s * C_ + c] * Wk[(s * C_ + c) * C_ + cj];
        wb[s * C_ + cj] = v;
        if (cj == 0) {
            float v2 = 0.f;
            for (int c = 0; c < C_; ++c)
                v2 += bq[s * C_ + c] * bk[s * C_ + c];
            cb[s] = v2;
        }
    }
}

// ---------------------------------------------------------------- K0b: fold Wout into Wv
// WosT[cj][o*4+s] = sum_c Wout[o][s*64+c] * Wv[c][cj]
// bos[o]          = bout[o] + sum_k Wout[o][k] * bv[k&63]
__global__ __launch_bounds__(256)
void k0b_wos(const float* __restrict__ Wout, const float* __restrict__ bout,
             const float* __restrict__ Wv, const float* __restrict__ bv,
             float* __restrict__ WosT, float* __restrict__ bos) {
    int cj = blockIdx.x;
    __shared__ float wvcol[C_];
    if (threadIdx.x < C_) wvcol[threadIdx.x] = Wv[threadIdx.x * C_ + cj];
    __syncthreads();
    int p = threadIdx.x;       // p = o*4 + s
    int o = p >> 2, s = p & 3;
    float acc = 0.f;
    for (int c = 0; c < C_; ++c)
        acc += Wout[o * (S_ * C_) + s * C_ + c] * wvcol[c];
    WosT[cj * 256 + p] = acc;
    if (cj == 0 && p < C_) {
        float a = bout[p];
        for (int k = 0; k < S_ * C_; ++k)
            a += Wout[p * (S_ * C_) + k] * bv[k & 63];
        bos[p] = a;
    }
}

// ---------------------------------------------------------------- K1: kq = Mt @ x_k + bM ; kb
// kq layout [n][s][ci][t][v] bf16 ; kb layout [n][s][t][v] fp32
__global__ __launch_bounds__(256)
void k1_kq(const float* __restrict__ x_k, const float* __restrict__ Mt,
           const float* __restrict__ bM, const float* __restrict__ wb,
           const float* __restrict__ cb, bf16* __restrict__ kq, float* __restrict__ kb) {
    __shared__ float xk_s[C_ * VK_]; // 12.8 KB
    int n = blockIdx.x >> 8, t = blockIdx.x & 255;
    for (int idx = threadIdx.x; idx < C_ * VK_; idx += 256)
        xk_s[idx] = x_k[((size_t)(n * C_) * T_ + t) * VK_ + (idx / VK_) * (T_ * VK_) + (idx % VK_)];
    __syncthreads();
    int s = threadIdx.x >> 6, ci = threadIdx.x & 63;
    float acc[VK_];
    float bm = bM[s * C_ + ci];
#pragma unroll
    for (int v = 0; v < VK_; ++v) acc[v] = bm;
    for (int cj = 0; cj < C_; ++cj) {
        float m = Mt[(s * C_ + cj) * C_ + ci]; // coalesced over ci lanes
#pragma unroll
        for (int v = 0; v < VK_; ++v) acc[v] += m * xk_s[cj * VK_ + v]; // broadcast
    }
    size_t base = (((size_t)(n * S_ + s) * C_ + ci) * T_ + t) * VK_;
#pragma unroll
    for (int v = 0; v < VK_; ++v) kq[base + v] = f2b(acc[v]);
    if (threadIdx.x < S_ * VK_) {
        int s2 = threadIdx.x / VK_, v = threadIdx.x % VK_;
        float a = cb[s2];
        for (int cj = 0; cj < C_; ++cj) a += wb[s2 * C_ + cj] * xk_s[cj * VK_ + v];
        kb[((size_t)(n * S_ + s2) * T_ + t) * VK_ + v] = a;
    }
}

// ---------------------------------------------------------------- K3: score partials
__global__ __launch_bounds__(256)
void k3_scores(const float* __restrict__ x_q, const bf16* __restrict__ kq,
               float* __restrict__ partial) {
    int chunk = blockIdx.x, l = blockIdx.y, ns = blockIdx.z;
    int n = ns >> 2, s = ns & 3;
    int t0 = chunk * TCH;
    int tlen = min(TCH, Tq_ - t0);
    __shared__ float xq_s[TCH * VQ_]; // 11.5 KB
    __shared__ float kq_s[TCH * VK_]; // 6.4 KB
    int tu = threadIdx.x % 18; // u = tu*5 + i, covers 90 exactly
    int tv = threadIdx.x / 18; // v = tv*4 + j (clamped)
    int vj[4];
#pragma unroll
    for (int j = 0; j < 4; ++j) vj[j] = min(tv * 4 + j, VK_ - 1);
    float acc[5][4] = {};
    for (int ci = 0; ci < C_; ++ci) {
        __syncthreads();
        for (int idx = threadIdx.x; idx < tlen * VQ_; idx += 256) {
            int tt = idx / VQ_, u = idx % VQ_;
            xq_s[idx] = x_q[((size_t)(n * C_ + ci) * T_ + t0 + tt) * VQ_ + u];
        }
        for (int idx = threadIdx.x; idx < tlen * VK_; idx += 256) {
            int tt = idx / VK_, v = idx % VK_;
            kq_s[idx] = b2f(kq[(((size_t)(n * S_ + s) * C_ + ci) * T_ + t0 + tt + l) * VK_ + v]);
        }
        __syncthreads();
        for (int tt = 0; tt < tlen; ++tt) {
            float xv[5], kv[4];
#pragma unroll
            for (int i = 0; i < 5; ++i) xv[i] = xq_s[tt * VQ_ + tu * 5 + i];
#pragma unroll
            for (int j = 0; j < 4; ++j) kv[j] = kq_s[tt * VK_ + vj[j]];
#pragma unroll
            for (int i = 0; i < 5; ++i)
#pragma unroll
                for (int j = 0; j < 4; ++j) acc[i][j] += xv[i] * kv[j];
        }
    }
    size_t base = (((size_t)ns * NL + l) * NCH + chunk) * (size_t)(VQ_ * VK_);
#pragma unroll
    for (int i = 0; i < 5; ++i) {
        int u = tu * 5 + i;
#pragma unroll
        for (int j = 0; j < 4; ++j) {
            int v = tv * 4 + j;
            if (v < VK_) partial[base + u * VK_ + v] = acc[i][j];
        }
    }
}

// ---------------------------------------------------------------- K4: combine lags + softmax
__global__ __launch_bounds__(256)
void k4_softmax(const float* __restrict__ partial, const float* __restrict__ kb,
                bf16* __restrict__ att) {
    int ns = blockIdx.x;
    __shared__ float kbs[NL * VK_];
    for (int idx = threadIdx.x; idx < NL * VK_; idx += 256) {
        int l = idx / VK_, v = idx % VK_;
        float a = 0.f;
        const float* p = kb + ((size_t)ns * T_ + l) * VK_ + v;
        for (int tt = 0; tt < Tq_; ++tt) a += p[tt * VK_];
        kbs[idx] = a;
    }
    __syncthreads();
    if (threadIdx.x < VQ_) {
        int u = threadIdx.x;
        const float inv_scale = rsqrtf((float)(C_ * Tq_));
        float pv[VK_];
        float pmax = -1e30f;
#pragma unroll
        for (int v = 0; v < VK_; ++v) {
            float sl[NL];
#pragma unroll
            for (int l = 0; l < NL; ++l) {
                float a = 0.f;
                for (int ch = 0; ch < NCH; ++ch)
                    a += partial[((((size_t)ns * NL + l) * NCH + ch) * VQ_ + u) * VK_ + v];
                sl[l] = (a + kbs[l * VK_ + v]) * inv_scale;
            }
            float mx = sl[0], mn = sl[0];
#pragma unroll
            for (int l = 1; l < NL; ++l) { mx = fmaxf(mx, sl[l]); mn += sl[l]; }
            pv[v] = 0.5f * (mx + mn * (1.f / NL));
            pmax = fmaxf(pmax, pv[v]);
        }
        float sum = 0.f;
#pragma unroll
        for (int v = 0; v < VK_; ++v) { pv[v] = __expf(pv[v] - pmax); sum += pv[v]; }
        float inv = 1.f / sum;
#pragma unroll
        for (int v = 0; v < VK_; ++v)
            att[((size_t)ns * VQ_ + u) * VK_ + v] = f2b(pv[v] * inv);
    }
}

// ---------------------------------------------------------------- K5: wv[n][t][o][s][v] = sum_cj Wos[o][s][cj] * x_v[n][cj][t][v]
__global__ __launch_bounds__(256)
void k5_wv(const float* __restrict__ x_v, const float* __restrict__ WosT,
           bf16* __restrict__ wv) {
    int t = blockIdx.x, n = blockIdx.y;
    __shared__ float xv_s[C_ * VK_];   // 12.8 KB
    __shared__ bf16  wos_s[C_ * 256];  // 32 KB, [cj][p]
    for (int idx = threadIdx.x; idx < C_ * VK_; idx += 256) {
        int cj = idx / VK_, v = idx % VK_;
        xv_s[idx] = x_v[((size_t)(n * C_ + cj) * T_ + t) * VK_ + v];
    }
    for (int idx = threadIdx.x; idx < C_ * 256; idx += 256)
        wos_s[idx] = f2b(WosT[idx]);
    __syncthreads();
    int p = threadIdx.x; // p = o*4+s
    float acc[VK_];
#pragma unroll
    for (int v = 0; v < VK_; ++v) acc[v] = 0.f;
    for (int cj = 0; cj < C_; ++cj) {
        float w = b2f(wos_s[cj * 256 + p]);
#pragma unroll
        for (int v = 0; v < VK_; ++v) acc[v] += w * xv_s[cj * VK_ + v];
    }
    size_t base = ((size_t)(n * T_ + t) * 256 + p) * VK_; // [n][t][o][s][v]
#pragma unroll
    for (int v = 0; v < VK_; ++v) wv[base + v] = f2b(acc[v]);
}

// ---------------------------------------------------------------- K6: out_pre[n][o][t][u] = bos[o] + sum_{s,v} att[n,s,u,v] * wv[n,t,o,s,v]
__global__ __launch_bounds__(256)
void k6_outpre(const bf16* __restrict__ att, const bf16* __restrict__ wv,
               const float* __restrict__ bos, bf16* __restrict__ out_pre) {
    int t = blockIdx.x, half = blockIdx.y, n = blockIdx.z;
    __shared__ float att_s[S_ * 45 * VK_]; // 36 KB  [s][ul][v]
    __shared__ bf16  wv_s[C_ * 200];       // 25.6 KB [o][s*50+v]
    for (int idx = threadIdx.x; idx < S_ * 45 * VK_; idx += 256) {
        int s = idx / (45 * VK_);
        int r = idx % (45 * VK_);
        int ul = r / VK_, v = r % VK_;
        att_s[idx] = b2f(att[(size_t)n * (S_ * VQ_ * VK_) + s * (VQ_ * VK_) + (half * 45 + ul) * VK_ + v]);
    }
    for (int idx = threadIdx.x; idx < C_ * 200; idx += 256)
        wv_s[idx] = wv[(size_t)(n * T_ + t) * (C_ * 200) + idx];
    __syncthreads();
    int to = threadIdx.x >> 5;   // 8 o per thread: o = to*8+i
    int tu = threadIdx.x & 31;   // 2 ul per thread: ul = tu + 32*j (clamp <45)
    int ul0 = tu, ul1 = tu + 32;
    int ur1 = min(ul1, 44);
    float acc[8][2];
#pragma unroll
    for (int i = 0; i < 8; ++i) {
        float b = bos[to * 8 + i];
        acc[i][0] = b; acc[i][1] = b;
    }
    for (int s = 0; s < S_; ++s) {
#pragma unroll 2
        for (int v = 0; v < VK_; ++v) {
            float a0 = att_s[(s * 45 + ul0) * VK_ + v];
            float a1 = att_s[(s * 45 + ur1) * VK_ + v];
#pragma unroll
            for (int i = 0; i < 8; ++i) {
                float w = b2f(wv_s[(to * 8 + i) * 200 + s * VK_ + v]);
                acc[i][0] += w * a0;
                acc[i][1] += w * a1;
            }
        }
    }
#pragma unroll
    for (int i = 0; i < 8; ++i) {
        int o = to * 8 + i;
        size_t base = ((size_t)(n * C_ + o) * T_ + t) * VQ_ + half * 45;
        out_pre[base + ul0] = f2b(acc[i][0]);
        if (ul1 < 45) out_pre[base + ul1] = f2b(acc[i][1]);
    }
}

// ---------------------------------------------------------------- K7: down conv (KR=64) as GEMM over cols
__global__ __launch_bounds__(256)
void k7_down(const float* __restrict__ X, const float* __restrict__ W,
             const float* __restrict__ bias, bf16* __restrict__ out) {
    int n = blockIdx.y;
    int col0 = blockIdx.x * 128;
    __shared__ float w_s[64 * 65];  // padded
    __shared__ float x_s[64 * 128];
    int to = threadIdx.x >> 5, tcol = threadIdx.x & 31;
    float acc[8][4] = {};
    for (int idx = threadIdx.x; idx < 64 * 64; idx += 256) {
        int o = idx >> 6, k = idx & 63;
        w_s[k * 65 + o] = W[o * C_ + k];
    }
    for (int idx = threadIdx.x; idx < 64 * 128; idx += 256) {
        int k = idx >> 7, c = idx & 127;
        x_s[k * 128 + c] = X[((size_t)n * C_ + k) * COLS + col0 + c];
    }
    __syncthreads();
#pragma unroll 4
    for (int k = 0; k < 64; ++k) {
        float wvr[8], xvr[4];
#pragma unroll
        for (int i = 0; i < 8; ++i) wvr[i] = w_s[k * 65 + to * 8 + i];
#pragma unroll
        for (int j = 0; j < 4; ++j) xvr[j] = x_s[k * 128 + tcol + 32 * j];
#pragma unroll
        for (int i = 0; i < 8; ++i)
#pragma unroll
            for (int j = 0; j < 4; ++j) acc[i][j] += wvr[i] * xvr[j];
    }
#pragma unroll
    for (int i = 0; i < 8; ++i) {
        int o = to * 8 + i;
        float b = bias[o];
#pragma unroll
        for (int j = 0; j < 4; ++j)
            out[((size_t)n * C_ + o) * COLS + col0 + tcol + 32 * j] = f2b(acc[i][j] + b);
    }
}

// ---------------------------------------------------------------- K8: per-channel sum/sumsq
__global__ __launch_bounds__(256)
void k8_stats(const bf16* __restrict__ out_pre, const bf16* __restrict__ d_pre,
              float* __restrict__ stats) {
    int path = blockIdx.x >> 9;
    int b = blockIdx.x & 511;
    int o = b >> 3, n = b & 7;
    const bf16* p = (path ? d_pre : out_pre) + ((size_t)n * C_ + o) * COLS;
    float s = 0.f, sq = 0.f;
    for (int i = threadIdx.x; i < COLS; i += 256) {
        float x = b2f(p[i]);
        s += x; sq += x * x;
    }
#pragma unroll
    for (int off = 32; off > 0; off >>= 1) {
        s  += __shfl_down(s, off, 64);
        sq += __shfl_down(sq, off, 64);
    }
    __shared__ float red[8];
    int wid = threadIdx.x >> 6, lane = threadIdx.x & 63;
    if (lane == 0) { red[wid * 2] = s; red[wid * 2 + 1] = sq; }
    __syncthreads();
    if (threadIdx.x == 0) {
        float S = 0.f, Q = 0.f;
        for (int w = 0; w < 4; ++w) { S += red[w * 2]; Q += red[w * 2 + 1]; }
        atomicAdd(&stats[path * 128 + o * 2], S);
        atomicAdd(&stats[path * 128 + o * 2 + 1], Q);
    }
}

// ---------------------------------------------------------------- K9: BN + BN + add + leaky relu (fp32 out)
__global__ __launch_bounds__(256)
void k9_final(const bf16* __restrict__ out_pre, const bf16* __restrict__ d_pre,
              const float* __restrict__ stats,
              const float* __restrict__ gamma_out, const float* __restrict__ beta_out,
              const float* __restrict__ gamma_down, const float* __restrict__ beta_down,
              float* __restrict__ out) {
    const float invM = 1.f / ((float)N_ * COLS);
    size_t total = (size_t)N_ * C_ * COLS;
    size_t stride = (size_t)gridDim.x * blockDim.x;
    for (size_t idx = (size_t)blockIdx.x * blockDim.x + threadIdx.x; idx < total; idx += stride) {
        int o = (int)((idx / COLS) % C_);
        float my = stats[o * 2] * invM;
        float vy = stats[o * 2 + 1] * invM - my * my;
        float md = stats[128 + o * 2] * invM;
        float vd = stats[128 + o * 2 + 1] * invM - md * md;
        float yn = (b2f(out_pre[idx]) - my) * rsqrtf(vy + EPSf) * gamma_out[o] + beta_out[o];
        float dn = (b2f(d_pre[idx]) - md) * rsqrtf(vd + EPSf) * gamma_down[o] + beta_down[o];
        float r = yn + dn;
        out[idx] = r > 0.f ? r : 0.1f * r;
    }
}

// ----------------------------------------------------------------
extern "C" void kernel_launch(void* const* d_in, const int* in_sizes, int n_in,
                              void* d_out, int out_size, void* d_ws, size_t ws_size,
                              hipStream_t stream) {
    (void)in_sizes; (void)n_in; (void)out_size; (void)ws_size;
    const float* x_q  = (const float*)d_in[0];
    const float* x_k  = (const float*)d_in[1];
    const float* x_v  = (const float*)d_in[2];
    const float* Wq   = (const float*)d_in[3];
    const float* bq   = (const float*)d_in[4];
    const float* Wk   = (const float*)d_in[5];
    const float* bk   = (const float*)d_in[6];
    const float* Wv   = (const float*)d_in[7];
    const float* bv   = (const float*)d_in[8];
    const float* Wout = (const float*)d_in[9];
    const float* bout = (const float*)d_in[10];
    const float* gamma_out  = (const float*)d_in[11];
    const float* beta_out   = (const float*)d_in[12];
    const float* Wdown = (const float*)d_in[13];
    const float* bdown = (const float*)d_in[14];
    const float* gamma_down = (const float*)d_in[15];
    const float* beta_down  = (const float*)d_in[16];

    char* w = (char*)d_ws;
    size_t off = 0;
    auto nxt = [&](size_t bytes) {
        char* p = w + off;
        off += (bytes + 255) & ~(size_t)255;
        return p;
    };
    float* Mt      = (float*)nxt((size_t)S_ * C_ * C_ * 4);
    float* bM      = (float*)nxt((size_t)S_ * C_ * 4);
    float* wbp     = (float*)nxt((size_t)S_ * C_ * 4);
    float* cbp     = (float*)nxt((size_t)S_ * 4);
    float* WosT    = (float*)nxt((size_t)C_ * 256 * 4);
    float* bos     = (float*)nxt((size_t)C_ * 4);
    bf16*  kq      = (bf16*)nxt((size_t)N_ * S_ * C_ * T_ * VK_ * 2);
    float* kb      = (float*)nxt((size_t)N_ * S_ * T_ * VK_ * 4);
    float* partial = (float*)nxt((size_t)N_ * S_ * NL * NCH * VQ_ * VK_ * 4);
    bf16*  att     = (bf16*)nxt((size_t)N_ * S_ * VQ_ * VK_ * 2);
    bf16*  wv      = (bf16*)nxt((size_t)N_ * T_ * 256 * VK_ * 2);
    bf16*  out_pre = (bf16*)nxt((size_t)N_ * C_ * T_ * VQ_ * 2);
    bf16*  d_pre   = (bf16*)nxt((size_t)N_ * C_ * T_ * VQ_ * 2);
    float* stats   = (float*)nxt(256 * 4);

    hipMemsetAsync(stats, 0, 256 * 4, stream);

    k0_precompute<<<S_ * C_, 64, 0, stream>>>(Wq, bq, Wk, bk, Mt, bM, wbp, cbp);
    k0b_wos<<<C_, 256, 0, stream>>>(Wout, bout, Wv, bv, WosT, bos);
    k1_kq<<<N_ * T_, 256, 0, stream>>>(x_k, Mt, bM, wbp, cbp, kq, kb);
    k3_scores<<<dim3(NCH, NL, N_ * S_), 256, 0, stream>>>(x_q, kq, partial);
    k4_softmax<<<N_ * S_, 256, 0, stream>>>(partial, kb, att);
    k5_wv<<<dim3(T_, N_), 256, 0, stream>>>(x_v, WosT, wv);
    k6_outpre<<<dim3(T_, 2, N_), 256, 0, stream>>>(att, wv, bos, out_pre);
    k7_down<<<dim3(COLS / 128, N_), 256, 0, stream>>>(x_q, Wdown, bdown, d_pre);
    k8_stats<<<1024, 256, 0, stream>>>(out_pre, d_pre, stats);
    k9_final<<<8192, 256, 0, stream>>>(out_pre, d_pre, stats, gamma_out, beta_out,
                                       gamma_down, beta_down, (float*)d_out);
}

// Round 3
// 741.195 us; speedup vs baseline: 1.6352x; 1.6352x over previous
//
#include <hip/hip_runtime.h>
#include <hip/hip_bf16.h>

typedef __hip_bfloat16 bf16;
typedef __attribute__((ext_vector_type(8))) short short8;
typedef __attribute__((ext_vector_type(16))) float f32x16;

__device__ __forceinline__ float b2f(bf16 x) { return __bfloat162float(x); }
__device__ __forceinline__ bf16  f2b(float x) { return __float2bfloat16(x); }
__device__ __forceinline__ short f2bs(float x) {
    bf16 h = __float2bfloat16(x);
    return *reinterpret_cast<short*>(&h);
}

constexpr int N_ = 8, C_ = 64, T_ = 256, VQ_ = 90, VK_ = 50, S_ = 4, L_ = 4;
constexpr int Tq_ = T_ - L_;     // 252
constexpr int NL  = L_ + 1;      // 5 lags
constexpr int COLS = T_ * VQ_;   // 23040
constexpr float EPSf = 1e-5f;
constexpr int NSL = 16;          // partial K-slices: 8 ci-groups x 2 t-halves

// ---------------------------------------------------------------- K0: fold Wq into key side
__global__ __launch_bounds__(64)
void k0_precompute(const float* __restrict__ Wq, const float* __restrict__ bq,
                   const float* __restrict__ Wk, const float* __restrict__ bk,
                   float* __restrict__ Mt, float* __restrict__ bM,
                   float* __restrict__ wb, float* __restrict__ cb) {
    int s  = blockIdx.x >> 6;
    int ci = blockIdx.x & 63;
    int cj = threadIdx.x;
    float m = 0.f;
    for (int c = 0; c < C_; ++c)
        m += Wq[(s * C_ + c) * C_ + ci] * Wk[(s * C_ + c) * C_ + cj];
    Mt[(s * C_ + cj) * C_ + ci] = m;
    if (cj == 0) {
        float v = 0.f;
        for (int c = 0; c < C_; ++c)
            v += Wq[(s * C_ + c) * C_ + ci] * bk[s * C_ + c];
        bM[s * C_ + ci] = v;
    }
    if (ci == 0) {
        float v = 0.f;
        for (int c = 0; c < C_; ++c)
            v += bq[s * C_ + c] * Wk[(s * C_ + c) * C_ + cj];
        wb[s * C_ + cj] = v;
        if (cj == 0) {
            float v2 = 0.f;
            for (int c = 0; c < C_; ++c)
                v2 += bq[s * C_ + c] * bk[s * C_ + c];
            cb[s] = v2;
        }
    }
}

// ---------------------------------------------------------------- K0b: fold Wout into Wv
__global__ __launch_bounds__(256)
void k0b_wos(const float* __restrict__ Wout, const float* __restrict__ bout,
             const float* __restrict__ Wv, const float* __restrict__ bv,
             float* __restrict__ WosT, float* __restrict__ bos) {
    int cj = blockIdx.x;
    __shared__ float wvcol[C_];
    if (threadIdx.x < C_) wvcol[threadIdx.x] = Wv[threadIdx.x * C_ + cj];
    __syncthreads();
    int p = threadIdx.x;       // p = o*4 + s
    int o = p >> 2, s = p & 3;
    float acc = 0.f;
    for (int c = 0; c < C_; ++c)
        acc += Wout[o * (S_ * C_) + s * C_ + c] * wvcol[c];
    WosT[cj * 256 + p] = acc;
    if (cj == 0 && p < C_) {
        float a = bout[p];
        for (int k = 0; k < S_ * C_; ++k)
            a += Wout[p * (S_ * C_) + k] * bv[k & 63];
        bos[p] = a;
    }
}

// ---------------------------------------------------------------- K0c: xqT[n][g][t][u96][cc8] bf16
__global__ __launch_bounds__(128)
void k0c_xqt(const float* __restrict__ xq, short* __restrict__ xqT) {
    int t = blockIdx.x, n = blockIdx.y;
    int u = threadIdx.x;
    if (u >= 96) return;
    for (int g = 0; g < 8; ++g) {
        short8 pack;
#pragma unroll
        for (int j = 0; j < 8; ++j) {
            float val = (u < 90) ? xq[((size_t)(n * 64 + g * 8 + j) * 256 + t) * 90 + u] : 0.f;
            pack[j] = f2bs(val);
        }
        *(short8*)(xqT + ((size_t)((n * 8 + g) * 256 + t) * 96 + u) * 8) = pack;
    }
}

// ---------------------------------------------------------------- K1: kq = Mt @ x_k + bM -> kqT[ns][g][t][v][cc] ; kb
__global__ __launch_bounds__(256)
void k1_kq(const float* __restrict__ x_k, const float* __restrict__ Mt,
           const float* __restrict__ bM, const float* __restrict__ wb,
           const float* __restrict__ cb, short* __restrict__ kqT, float* __restrict__ kb) {
    __shared__ float xk_s[C_ * VK_];            // 12.8 KB
    __shared__ __align__(16) short kst[32 * VK_ * 8]; // 25.6 KB [sg][v][cc]
    int n = blockIdx.x >> 8, t = blockIdx.x & 255;
    for (int idx = threadIdx.x; idx < C_ * VK_; idx += 256)
        xk_s[idx] = x_k[((size_t)(n * C_ + idx / VK_) * T_ + t) * VK_ + idx % VK_];
    __syncthreads();
    int s = threadIdx.x >> 6, ci = threadIdx.x & 63;
    float acc[VK_];
    float bm = bM[s * C_ + ci];
#pragma unroll
    for (int v = 0; v < VK_; ++v) acc[v] = bm;
    for (int cj = 0; cj < C_; ++cj) {
        float m = Mt[(s * C_ + cj) * C_ + ci];
#pragma unroll
        for (int v = 0; v < VK_; ++v) acc[v] += m * xk_s[cj * VK_ + v];
    }
    short* dst = kst + ((s * 8 + (ci >> 3)) * VK_) * 8 + (ci & 7);
#pragma unroll
    for (int v = 0; v < VK_; ++v) dst[v * 8] = f2bs(acc[v]);
    if (threadIdx.x < S_ * VK_) {
        int s2 = threadIdx.x / VK_, v = threadIdx.x % VK_;
        float a = cb[s2];
        for (int cj = 0; cj < C_; ++cj) a += wb[s2 * C_ + cj] * xk_s[cj * VK_ + v];
        kb[((size_t)(n * S_ + s2) * T_ + t) * VK_ + v] = a;
    }
    __syncthreads();
    for (int c = threadIdx.x; c < 32 * VK_; c += 256) {
        int sg = c / VK_, v = c % VK_;
        size_t doff = (((size_t)(n * 4 + (sg >> 3)) * 8 + (sg & 7)) * 256 + t) * (VK_ * 8) + v * 8;
        *(short8*)(kqT + doff) = *(const short8*)(kst + c * 8);
    }
}

// ---------------------------------------------------------------- K3: MFMA scores
// grid (gx=g*2+half, ns). lags folded into N: n = l*50+v, N=256 (8 tiles of 32).
__global__ __launch_bounds__(256)
void k3_mfma(const short* __restrict__ xqT, const short* __restrict__ kqT,
             float* __restrict__ partial) {
    int gx = blockIdx.x;       // 0..15
    int g = gx >> 1, half = gx & 1;
    int ns = blockIdx.y;
    int n = ns >> 2;
    __shared__ __align__(16) short xa[12 * 96 * 8];    // 18432 B
    __shared__ __align__(16) short kbs[16 * VK_ * 8];  // 12800 B
    int tid = threadIdx.x;
    int wave = tid >> 6, lane = tid & 63;
    int q = lane >> 5, nl = lane & 31;
    // per-lane B constants for the wave's two n-tiles
    int n1 = wave * 64 + nl, n2 = n1 + 32;
    int nc1 = min(n1, 249), nc2 = min(n2, 249);
    int l1 = nc1 / VK_, v1 = nc1 % VK_;
    int l2 = nc2 / VK_, v2 = nc2 % VK_;
    int bo1 = ((q + l1) * VK_ + v1) * 8;
    int bo2 = ((q + l2) * VK_ + v2) * 8;
    int ao = (q * 96 + nl) * 8;
    f32x16 acc[6];
#pragma unroll
    for (int i = 0; i < 6; ++i)
#pragma unroll
        for (int r = 0; r < 16; ++r) acc[i][r] = 0.f;
    const short* asrc = xqT + (size_t)(n * 8 + g) * 256 * 768;
    const short* bsrc = kqT + (size_t)(ns * 8 + g) * 256 * 400;
    int c0 = half * 10, c1 = half ? 21 : 10;
    for (int ch = c0; ch < c1; ++ch) {
        int t0 = ch * 12;
        __syncthreads();
        {
            const short* as = asrc + t0 * 768;
            for (int i = tid; i < 1152; i += 256)
                *(short8*)(xa + i * 8) = *(const short8*)(as + i * 8);
            const short* bs = bsrc + t0 * 400;
            for (int i = tid; i < 800; i += 256)
                *(short8*)(kbs + i * 8) = *(const short8*)(bs + i * 8);
        }
        __syncthreads();
#pragma unroll
        for (int ts = 0; ts < 6; ++ts) {
            short8 a0 = *(const short8*)(xa + ao + ts * 1536);
            short8 a1 = *(const short8*)(xa + ao + 256 + ts * 1536);
            short8 a2 = *(const short8*)(xa + ao + 512 + ts * 1536);
            short8 b0 = *(const short8*)(kbs + bo1 + ts * 800);
            short8 b1 = *(const short8*)(kbs + bo2 + ts * 800);
            acc[0] = __builtin_amdgcn_mfma_f32_32x32x16_bf16(a0, b0, acc[0], 0, 0, 0);
            acc[1] = __builtin_amdgcn_mfma_f32_32x32x16_bf16(a1, b0, acc[1], 0, 0, 0);
            acc[2] = __builtin_amdgcn_mfma_f32_32x32x16_bf16(a2, b0, acc[2], 0, 0, 0);
            acc[3] = __builtin_amdgcn_mfma_f32_32x32x16_bf16(a0, b1, acc[3], 0, 0, 0);
            acc[4] = __builtin_amdgcn_mfma_f32_32x32x16_bf16(a1, b1, acc[4], 0, 0, 0);
            acc[5] = __builtin_amdgcn_mfma_f32_32x32x16_bf16(a2, b1, acc[5], 0, 0, 0);
        }
    }
    // store: partial[((ns*5+l)*90 + u)*16 + gx]*50 + v
#pragma unroll
    for (int inb = 0; inb < 2; ++inb) {
        int ng = wave * 64 + inb * 32 + nl;
        if (ng < 250) {
            int l = ng / VK_, v = ng % VK_;
            float* pb = partial + ((((size_t)ns * 5 + l) * 90) * NSL + gx) * VK_ + v;
#pragma unroll
            for (int iu = 0; iu < 3; ++iu) {
#pragma unroll
                for (int r = 0; r < 16; ++r) {
                    int u = iu * 32 + (r & 3) + 8 * (r >> 2) + 4 * q;
                    if (u < 90) pb[(size_t)u * NSL * VK_] = acc[inb * 3 + iu][r];
                }
            }
        }
    }
}

// ---------------------------------------------------------------- K3b: kbsum[ns][l][v] = sum_t kb[ns][t+l][v]
__global__ __launch_bounds__(256)
void k3b_kbsum(const float* __restrict__ kb, float* __restrict__ kbsum) {
    int ns = blockIdx.x;
    int idx = threadIdx.x;
    if (idx < NL * VK_) {
        int l = idx / VK_, v = idx % VK_;
        float a = 0.f;
        for (int tt = 0; tt < Tq_; ++tt) a += kb[((size_t)ns * T_ + tt + l) * VK_ + v];
        kbsum[(ns * NL + l) * VK_ + v] = a;
    }
}

// ---------------------------------------------------------------- K4: reduce slices + combine lags + softmax
__global__ __launch_bounds__(256)
void k4_softmax(const float* __restrict__ partial, const float* __restrict__ kbsum,
                bf16* __restrict__ att) {
    int ug = blockIdx.x;  // 0..5 (15 u each)
    int ns = blockIdx.y;
    int u0 = ug * 15;
    __shared__ float sred[NL * 15 * VK_]; // 15 KB
    for (int idx = threadIdx.x; idx < NL * 15 * VK_; idx += 256) {
        int l = idx / (15 * VK_), r = idx % (15 * VK_);
        int u = r / VK_, v = r % VK_;
        const float* p = partial + (((size_t)(ns * NL + l) * 90 + u0 + u) * NSL) * VK_ + v;
        float a = 0.f;
#pragma unroll
        for (int sl = 0; sl < NSL; ++sl) a += p[sl * VK_];
        sred[idx] = a;
    }
    __syncthreads();
    if (threadIdx.x < 15) {
        int u = threadIdx.x;
        const float inv_scale = rsqrtf((float)(C_ * Tq_));
        float pv[VK_];
        float pmax = -1e30f;
#pragma unroll
        for (int v = 0; v < VK_; ++v) {
            float mx = -1e30f, mn = 0.f;
#pragma unroll
            for (int l = 0; l < NL; ++l) {
                float sl = (sred[(l * 15 + u) * VK_ + v] + kbsum[(ns * NL + l) * VK_ + v]) * inv_scale;
                mx = fmaxf(mx, sl); mn += sl;
            }
            pv[v] = 0.5f * (mx + mn * (1.f / NL));
            pmax = fmaxf(pmax, pv[v]);
        }
        float sum = 0.f;
#pragma unroll
        for (int v = 0; v < VK_; ++v) { pv[v] = __expf(pv[v] - pmax); sum += pv[v]; }
        float inv = 1.f / sum;
#pragma unroll
        for (int v = 0; v < VK_; ++v)
            att[((size_t)ns * VQ_ + u0 + u) * VK_ + v] = f2b(pv[v] * inv);
    }
}

// ---------------------------------------------------------------- K5: wv[n][t][p][v] = sum_cj Wos[p][cj] * x_v[n][cj][t][v]
__global__ __launch_bounds__(256)
void k5_wv(const float* __restrict__ x_v, const float* __restrict__ WosT,
           bf16* __restrict__ wv) {
    int t = blockIdx.x, n = blockIdx.y;
    __shared__ float xv_s[C_ * VK_];   // 12.8 KB
    __shared__ bf16  wos_s[C_ * 256];  // 32 KB, [cj][p]
    for (int idx = threadIdx.x; idx < C_ * VK_; idx += 256) {
        int cj = idx / VK_, v = idx % VK_;
        xv_s[idx] = x_v[((size_t)(n * C_ + cj) * T_ + t) * VK_ + v];
    }
    for (int idx = threadIdx.x; idx < C_ * 256; idx += 256)
        wos_s[idx] = f2b(WosT[idx]);
    __syncthreads();
    int p = threadIdx.x; // p = o*4+s
    float acc[VK_];
#pragma unroll
    for (int v = 0; v < VK_; ++v) acc[v] = 0.f;
    for (int cj = 0; cj < C_; ++cj) {
        float w = b2f(wos_s[cj * 256 + p]);
#pragma unroll
        for (int v = 0; v < VK_; ++v) acc[v] += w * xv_s[cj * VK_ + v];
    }
    size_t base = ((size_t)(n * T_ + t) * 256 + p) * VK_;
#pragma unroll
    for (int v = 0; v < VK_; ++v) wv[base + v] = f2b(acc[v]);
}

// ---------------------------------------------------------------- K6: out_pre = bos + sum_{s,v} att * wv
__global__ __launch_bounds__(256)
void k6_outpre(const bf16* __restrict__ att, const bf16* __restrict__ wv,
               const float* __restrict__ bos, bf16* __restrict__ out_pre) {
    int t = blockIdx.x, half = blockIdx.y, n = blockIdx.z;
    __shared__ float att_s[S_ * 45 * VK_]; // 36 KB  [s][ul][v]
    __shared__ bf16  wv_s[C_ * 200];       // 25.6 KB [o][s*50+v]
    for (int idx = threadIdx.x; idx < S_ * 45 * VK_; idx += 256) {
        int s = idx / (45 * VK_);
        int r = idx % (45 * VK_);
        int ul = r / VK_, v = r % VK_;
        att_s[idx] = b2f(att[(size_t)(n * S_ + s) * (VQ_ * VK_) + (half * 45 + ul) * VK_ + v]);
    }
    for (int idx = threadIdx.x; idx < C_ * 200; idx += 256)
        wv_s[idx] = wv[(size_t)(n * T_ + t) * (C_ * 200 / 50) * VK_ + idx];
    __syncthreads();
    int to = threadIdx.x >> 5;
    int tu = threadIdx.x & 31;
    int ul0 = tu, ul1 = tu + 32;
    int ur1 = min(ul1, 44);
    float acc2[8][2];
#pragma unroll
    for (int i = 0; i < 8; ++i) {
        float b = bos[to * 8 + i];
        acc2[i][0] = b; acc2[i][1] = b;
    }
    for (int s = 0; s < S_; ++s) {
#pragma unroll 2
        for (int v = 0; v < VK_; ++v) {
            float a0 = att_s[(s * 45 + ul0) * VK_ + v];
            float a1 = att_s[(s * 45 + ur1) * VK_ + v];
#pragma unroll
            for (int i = 0; i < 8; ++i) {
                float w = b2f(wv_s[(to * 8 + i) * 200 + s * VK_ + v]);
                acc2[i][0] += w * a0;
                acc2[i][1] += w * a1;
            }
        }
    }
#pragma unroll
    for (int i = 0; i < 8; ++i) {
        int o = to * 8 + i;
        size_t base = ((size_t)(n * C_ + o) * T_ + t) * VQ_ + half * 45;
        out_pre[base + ul0] = f2b(acc2[i][0]);
        if (ul1 < 45) out_pre[base + ul1] = f2b(acc2[i][1]);
    }
}

// ---------------------------------------------------------------- K7: down conv (KR=64)
__global__ __launch_bounds__(256)
void k7_down(const float* __restrict__ X, const float* __restrict__ W,
             const float* __restrict__ bias, bf16* __restrict__ out) {
    int n = blockIdx.y;
    int col0 = blockIdx.x * 128;
    __shared__ float w_s[64 * 65];
    __shared__ float x_s[64 * 128];
    int to = threadIdx.x >> 5, tcol = threadIdx.x & 31;
    float acc[8][4] = {};
    for (int idx = threadIdx.x; idx < 64 * 64; idx += 256) {
        int o = idx >> 6, k = idx & 63;
        w_s[k * 65 + o] = W[o * C_ + k];
    }
    for (int idx = threadIdx.x; idx < 64 * 128; idx += 256) {
        int k = idx >> 7, c = idx & 127;
        x_s[k * 128 + c] = X[((size_t)n * C_ + k) * COLS + col0 + c];
    }
    __syncthreads();
#pragma unroll 4
    for (int k = 0; k < 64; ++k) {
        float wvr[8], xvr[4];
#pragma unroll
        for (int i = 0; i < 8; ++i) wvr[i] = w_s[k * 65 + to * 8 + i];
#pragma unroll
        for (int j = 0; j < 4; ++j) xvr[j] = x_s[k * 128 + tcol + 32 * j];
#pragma unroll
        for (int i = 0; i < 8; ++i)
#pragma unroll
            for (int j = 0; j < 4; ++j) acc[i][j] += wvr[i] * xvr[j];
    }
#pragma unroll
    for (int i = 0; i < 8; ++i) {
        int o = to * 8 + i;
        float b = bias[o];
#pragma unroll
        for (int j = 0; j < 4; ++j)
            out[((size_t)n * C_ + o) * COLS + col0 + tcol + 32 * j] = f2b(acc[i][j] + b);
    }
}

// ---------------------------------------------------------------- K8: per-channel sum/sumsq
__global__ __launch_bounds__(256)
void k8_stats(const bf16* __restrict__ out_pre, const bf16* __restrict__ d_pre,
              float* __restrict__ stats) {
    int path = blockIdx.x >> 9;
    int b = blockIdx.x & 511;
    int o = b >> 3, n = b & 7;
    const bf16* p = (path ? d_pre : out_pre) + ((size_t)n * C_ + o) * COLS;
    float s = 0.f, sq = 0.f;
    for (int i = threadIdx.x; i < COLS; i += 256) {
        float x = b2f(p[i]);
        s += x; sq += x * x;
    }
#pragma unroll
    for (int off = 32; off > 0; off >>= 1) {
        s  += __shfl_down(s, off, 64);
        sq += __shfl_down(sq, off, 64);
    }
    __shared__ float red[8];
    int wid = threadIdx.x >> 6, lane = threadIdx.x & 63;
    if (lane == 0) { red[wid * 2] = s; red[wid * 2 + 1] = sq; }
    __syncthreads();
    if (threadIdx.x == 0) {
        float S = 0.f, Q = 0.f;
        for (int w2 = 0; w2 < 4; ++w2) { S += red[w2 * 2]; Q += red[w2 * 2 + 1]; }
        atomicAdd(&stats[path * 128 + o * 2], S);
        atomicAdd(&stats[path * 128 + o * 2 + 1], Q);
    }
}

// ---------------------------------------------------------------- K9: BN + BN + add + leaky relu (fp32 out)
__global__ __launch_bounds__(256)
void k9_final(const bf16* __restrict__ out_pre, const bf16* __restrict__ d_pre,
              const float* __restrict__ stats,
              const float* __restrict__ gamma_out, const float* __restrict__ beta_out,
              const float* __restrict__ gamma_down, const float* __restrict__ beta_down,
              float* __restrict__ out) {
    const float invM = 1.f / ((float)N_ * COLS);
    size_t total = (size_t)N_ * C_ * COLS;
    size_t stride = (size_t)gridDim.x * blockDim.x;
    for (size_t idx = (size_t)blockIdx.x * blockDim.x + threadIdx.x; idx < total; idx += stride) {
        int o = (int)((idx / COLS) % C_);
        float my = stats[o * 2] * invM;
        float vy = stats[o * 2 + 1] * invM - my * my;
        float md = stats[128 + o * 2] * invM;
        float vd = stats[128 + o * 2 + 1] * invM - md * md;
        float yn = (b2f(out_pre[idx]) - my) * rsqrtf(vy + EPSf) * gamma_out[o] + beta_out[o];
        float dn = (b2f(d_pre[idx]) - md) * rsqrtf(vd + EPSf) * gamma_down[o] + beta_down[o];
        float r = yn + dn;
        out[idx] = r > 0.f ? r : 0.1f * r;
    }
}

// ----------------------------------------------------------------
extern "C" void kernel_launch(void* const* d_in, const int* in_sizes, int n_in,
                              void* d_out, int out_size, void* d_ws, size_t ws_size,
                              hipStream_t stream) {
    (void)in_sizes; (void)n_in; (void)out_size; (void)ws_size;
    const float* x_q  = (const float*)d_in[0];
    const float* x_k  = (const float*)d_in[1];
    const float* x_v  = (const float*)d_in[2];
    const float* Wq   = (const float*)d_in[3];
    const float* bq   = (const float*)d_in[4];
    const float* Wk   = (const float*)d_in[5];
    const float* bk   = (const float*)d_in[6];
    const float* Wv   = (const float*)d_in[7];
    const float* bv   = (const float*)d_in[8];
    const float* Wout = (const float*)d_in[9];
    const float* bout = (const float*)d_in[10];
    const float* gamma_out  = (const float*)d_in[11];
    const float* beta_out   = (const float*)d_in[12];
    const float* Wdown = (const float*)d_in[13];
    const float* bdown = (const float*)d_in[14];
    const float* gamma_down = (const float*)d_in[15];
    const float* beta_down  = (const float*)d_in[16];

    char* w = (char*)d_ws;
    size_t off = 0;
    auto nxt = [&](size_t bytes) {
        char* p = w + off;
        off += (bytes + 255) & ~(size_t)255;
        return p;
    };
    float* Mt      = (float*)nxt((size_t)S_ * C_ * C_ * 4);
    float* bM      = (float*)nxt((size_t)S_ * C_ * 4);
    float* wbp     = (float*)nxt((size_t)S_ * C_ * 4);
    float* cbp     = (float*)nxt((size_t)S_ * 4);
    float* WosT    = (float*)nxt((size_t)C_ * 256 * 4);
    float* bos     = (float*)nxt((size_t)C_ * 4);
    short* xqT     = (short*)nxt((size_t)N_ * 8 * T_ * 96 * 8 * 2);       // 25.2 MB
    short* kqT     = (short*)nxt((size_t)N_ * S_ * 8 * T_ * VK_ * 8 * 2); // 52.4 MB
    float* kb      = (float*)nxt((size_t)N_ * S_ * T_ * VK_ * 4);         // 6.6 MB
    float* kbsum   = (float*)nxt((size_t)N_ * S_ * NL * VK_ * 4);
    float* partial = (float*)nxt((size_t)N_ * S_ * NL * 90 * NSL * VK_ * 4); // 46 MB
    bf16*  att     = (bf16*)nxt((size_t)N_ * S_ * VQ_ * VK_ * 2);
    bf16*  wv      = (bf16*)nxt((size_t)N_ * T_ * 256 * VK_ * 2);         // 52.4 MB
    bf16*  out_pre = (bf16*)nxt((size_t)N_ * C_ * T_ * VQ_ * 2);          // 23.6 MB
    bf16*  d_pre   = (bf16*)nxt((size_t)N_ * C_ * T_ * VQ_ * 2);          // 23.6 MB
    float* stats   = (float*)nxt(256 * 4);

    hipMemsetAsync(stats, 0, 256 * 4, stream);

    k0_precompute<<<S_ * C_, 64, 0, stream>>>(Wq, bq, Wk, bk, Mt, bM, wbp, cbp);
    k0b_wos<<<C_, 256, 0, stream>>>(Wout, bout, Wv, bv, WosT, bos);
    k0c_xqt<<<dim3(T_, N_), 128, 0, stream>>>(x_q, xqT);
    k1_kq<<<N_ * T_, 256, 0, stream>>>(x_k, Mt, bM, wbp, cbp, kqT, kb);
    k3b_kbsum<<<N_ * S_, 256, 0, stream>>>(kb, kbsum);
    k3_mfma<<<dim3(NSL, N_ * S_), 256, 0, stream>>>(xqT, kqT, partial);
    k4_softmax<<<dim3(6, N_ * S_), 256, 0, stream>>>(partial, kbsum, att);
    k5_wv<<<dim3(T_, N_), 256, 0, stream>>>(x_v, WosT, wv);
    k6_outpre<<<dim3(T_, 2, N_), 256, 0, stream>>>(att, wv, bos, out_pre);
    k7_down<<<dim3(COLS / 128, N_), 256, 0, stream>>>(x_q, Wdown, bdown, d_pre);
    k8_stats<<<1024, 256, 0, stream>>>(out_pre, d_pre, stats);
    k9_final<<<8192, 256, 0, stream>>>(out_pre, d_pre, stats, gamma_out, beta_out,
                                       gamma_down, beta_down, (float*)d_out);
}

// Round 4
// 575.559 us; speedup vs baseline: 2.1058x; 1.2878x over previous
//
#include <hip/hip_runtime.h>
#include <hip/hip_bf16.h>

typedef __hip_bfloat16 bf16;
typedef __attribute__((ext_vector_type(8))) short short8;
typedef __attribute__((ext_vector_type(16))) float f32x16;

__device__ __forceinline__ float b2f(bf16 x) { return __bfloat162float(x); }
__device__ __forceinline__ bf16  f2b(float x) { return __float2bfloat16(x); }
__device__ __forceinline__ short f2bs(float x) {
    bf16 h = __float2bfloat16(x);
    return *reinterpret_cast<short*>(&h);
}

constexpr int N_ = 8, C_ = 64, T_ = 256, VQ_ = 90, VK_ = 50, S_ = 4, L_ = 4;
constexpr int Tq_ = T_ - L_;     // 252
constexpr int NL  = L_ + 1;      // 5 lags
constexpr int COLS = T_ * VQ_;   // 23040
constexpr float EPSf = 1e-5f;
constexpr int NSL = 16;          // partial K-slices: 8 ci-groups x 2 t-halves
constexpr int KG  = 26;          // k-groups for y-path K=200 (pad to 208), group 25 = zeros
constexpr int KSTR = 520;        // kst LDS row stride (shorts), breaks bank alignment

// ---------------------------------------------------------------- K0: fold Wq into key side
__global__ __launch_bounds__(64)
void k0_precompute(const float* __restrict__ Wq, const float* __restrict__ bq,
                   const float* __restrict__ Wk, const float* __restrict__ bk,
                   float* __restrict__ Mt, float* __restrict__ bM,
                   float* __restrict__ wb, float* __restrict__ cb) {
    int s  = blockIdx.x >> 6;
    int ci = blockIdx.x & 63;
    int cj = threadIdx.x;
    float m = 0.f;
    for (int c = 0; c < C_; ++c)
        m += Wq[(s * C_ + c) * C_ + ci] * Wk[(s * C_ + c) * C_ + cj];
    Mt[(s * C_ + cj) * C_ + ci] = m;
    if (cj == 0) {
        float v = 0.f;
        for (int c = 0; c < C_; ++c)
            v += Wq[(s * C_ + c) * C_ + ci] * bk[s * C_ + c];
        bM[s * C_ + ci] = v;
    }
    if (ci == 0) {
        float v = 0.f;
        for (int c = 0; c < C_; ++c)
            v += bq[s * C_ + c] * Wk[(s * C_ + c) * C_ + cj];
        wb[s * C_ + cj] = v;
        if (cj == 0) {
            float v2 = 0.f;
            for (int c = 0; c < C_; ++c)
                v2 += bq[s * C_ + c] * bk[s * C_ + c];
            cb[s] = v2;
        }
    }
}

// ---------------------------------------------------------------- K0b: fold Wout into Wv
__global__ __launch_bounds__(256)
void k0b_wos(const float* __restrict__ Wout, const float* __restrict__ bout,
             const float* __restrict__ Wv, const float* __restrict__ bv,
             bf16* __restrict__ WosTb, float* __restrict__ bos) {
    int cj = blockIdx.x;
    __shared__ float wvcol[C_];
    if (threadIdx.x < C_) wvcol[threadIdx.x] = Wv[threadIdx.x * C_ + cj];
    __syncthreads();
    int p = threadIdx.x;       // p = o*4 + s
    int o = p >> 2, s = p & 3;
    float acc = 0.f;
    for (int c = 0; c < C_; ++c)
        acc += Wout[o * (S_ * C_) + s * C_ + c] * wvcol[c];
    WosTb[cj * 256 + p] = f2b(acc);
    if (cj == 0 && p < C_) {
        float a = bout[p];
        for (int k = 0; k < S_ * C_; ++k)
            a += Wout[p * (S_ * C_) + k] * bv[k & 63];
        bos[p] = a;
    }
}

// ---------------------------------------------------------------- K0c: xqT[n][g][t][u96][cc8] bf16
__global__ __launch_bounds__(128)
void k0c_xqt(const float* __restrict__ xq, short* __restrict__ xqT) {
    int t = blockIdx.x, n = blockIdx.y;
    int u = threadIdx.x;
    if (u >= 96) return;
    for (int g = 0; g < 8; ++g) {
        short8 pack;
#pragma unroll
        for (int j = 0; j < 8; ++j) {
            float val = (u < 90) ? xq[((size_t)(n * 64 + g * 8 + j) * 256 + t) * 90 + u] : 0.f;
            pack[j] = f2bs(val);
        }
        *(short8*)(xqT + ((size_t)((n * 8 + g) * 256 + t) * 96 + u) * 8) = pack;
    }
}

// ---------------------------------------------------------------- K1: kq = Mt @ x_k + bM -> kqT[ns][g][t][v][cc] ; kb
__global__ __launch_bounds__(256)
void k1_kq(const float* __restrict__ x_k, const float* __restrict__ Mt,
           const float* __restrict__ bM, const float* __restrict__ wb,
           const float* __restrict__ cb, short* __restrict__ kqT, float* __restrict__ kb) {
    __shared__ float xk_s[C_ * VK_];            // 12.8 KB
    __shared__ __align__(16) short kst[32 * VK_ * 8]; // 25.6 KB [sg][v][cc]
    int n = blockIdx.x >> 8, t = blockIdx.x & 255;
    for (int idx = threadIdx.x; idx < C_ * VK_; idx += 256)
        xk_s[idx] = x_k[((size_t)(n * C_ + idx / VK_) * T_ + t) * VK_ + idx % VK_];
    __syncthreads();
    int s = threadIdx.x >> 6, ci = threadIdx.x & 63;
    float acc[VK_];
    float bm = bM[s * C_ + ci];
#pragma unroll
    for (int v = 0; v < VK_; ++v) acc[v] = bm;
    for (int cj = 0; cj < C_; ++cj) {
        float m = Mt[(s * C_ + cj) * C_ + ci];
#pragma unroll
        for (int v = 0; v < VK_; ++v) acc[v] += m * xk_s[cj * VK_ + v];
    }
    short* dst = kst + ((s * 8 + (ci >> 3)) * VK_) * 8 + (ci & 7);
#pragma unroll
    for (int v = 0; v < VK_; ++v) dst[v * 8] = f2bs(acc[v]);
    if (threadIdx.x < S_ * VK_) {
        int s2 = threadIdx.x / VK_, v = threadIdx.x % VK_;
        float a = cb[s2];
        for (int cj = 0; cj < C_; ++cj) a += wb[s2 * C_ + cj] * xk_s[cj * VK_ + v];
        kb[((size_t)(n * S_ + s2) * T_ + t) * VK_ + v] = a;
    }
    __syncthreads();
    for (int c = threadIdx.x; c < 32 * VK_; c += 256) {
        int sg = c / VK_, v = c % VK_;
        size_t doff = (((size_t)(n * 4 + (sg >> 3)) * 8 + (sg & 7)) * 256 + t) * (VK_ * 8) + v * 8;
        *(short8*)(kqT + doff) = *(const short8*)(kst + c * 8);
    }
}

// ---------------------------------------------------------------- K3: MFMA scores
__global__ __launch_bounds__(256)
void k3_mfma(const short* __restrict__ xqT, const short* __restrict__ kqT,
             float* __restrict__ partial) {
    int gx = blockIdx.x;       // 0..15
    int g = gx >> 1, half = gx & 1;
    int ns = blockIdx.y;
    int n = ns >> 2;
    __shared__ __align__(16) short xa[12 * 96 * 8];    // 18432 B
    __shared__ __align__(16) short kbs[16 * VK_ * 8];  // 12800 B
    int tid = threadIdx.x;
    int wave = tid >> 6, lane = tid & 63;
    int q = lane >> 5, nl = lane & 31;
    int n1 = wave * 64 + nl, n2 = n1 + 32;
    int nc1 = min(n1, 249), nc2 = min(n2, 249);
    int l1 = nc1 / VK_, v1 = nc1 % VK_;
    int l2 = nc2 / VK_, v2 = nc2 % VK_;
    int bo1 = ((q + l1) * VK_ + v1) * 8;
    int bo2 = ((q + l2) * VK_ + v2) * 8;
    int ao = (q * 96 + nl) * 8;
    f32x16 acc[6];
#pragma unroll
    for (int i = 0; i < 6; ++i)
#pragma unroll
        for (int r = 0; r < 16; ++r) acc[i][r] = 0.f;
    const short* asrc = xqT + (size_t)(n * 8 + g) * 256 * 768;
    const short* bsrc = kqT + (size_t)(ns * 8 + g) * 256 * 400;
    int c0 = half * 10, c1 = half ? 21 : 10;
    for (int ch = c0; ch < c1; ++ch) {
        int t0 = ch * 12;
        __syncthreads();
        {
            const short* as = asrc + t0 * 768;
            for (int i = tid; i < 1152; i += 256)
                *(short8*)(xa + i * 8) = *(const short8*)(as + i * 8);
            const short* bs = bsrc + t0 * 400;
            for (int i = tid; i < 800; i += 256)
                *(short8*)(kbs + i * 8) = *(const short8*)(bs + i * 8);
        }
        __syncthreads();
#pragma unroll
        for (int ts = 0; ts < 6; ++ts) {
            short8 a0 = *(const short8*)(xa + ao + ts * 1536);
            short8 a1 = *(const short8*)(xa + ao + 256 + ts * 1536);
            short8 a2 = *(const short8*)(xa + ao + 512 + ts * 1536);
            short8 b0 = *(const short8*)(kbs + bo1 + ts * 800);
            short8 b1 = *(const short8*)(kbs + bo2 + ts * 800);
            acc[0] = __builtin_amdgcn_mfma_f32_32x32x16_bf16(a0, b0, acc[0], 0, 0, 0);
            acc[1] = __builtin_amdgcn_mfma_f32_32x32x16_bf16(a1, b0, acc[1], 0, 0, 0);
            acc[2] = __builtin_amdgcn_mfma_f32_32x32x16_bf16(a2, b0, acc[2], 0, 0, 0);
            acc[3] = __builtin_amdgcn_mfma_f32_32x32x16_bf16(a0, b1, acc[3], 0, 0, 0);
            acc[4] = __builtin_amdgcn_mfma_f32_32x32x16_bf16(a1, b1, acc[4], 0, 0, 0);
            acc[5] = __builtin_amdgcn_mfma_f32_32x32x16_bf16(a2, b1, acc[5], 0, 0, 0);
        }
    }
#pragma unroll
    for (int inb = 0; inb < 2; ++inb) {
        int ng = wave * 64 + inb * 32 + nl;
        if (ng < 250) {
            int l = ng / VK_, v = ng % VK_;
            float* pb = partial + ((((size_t)ns * 5 + l) * 90) * NSL + gx) * VK_ + v;
#pragma unroll
            for (int iu = 0; iu < 3; ++iu) {
#pragma unroll
                for (int r = 0; r < 16; ++r) {
                    int u = iu * 32 + (r & 3) + 8 * (r >> 2) + 4 * q;
                    if (u < 90) pb[(size_t)u * NSL * VK_] = acc[inb * 3 + iu][r];
                }
            }
        }
    }
}

// ---------------------------------------------------------------- K3b: kbsum[ns][l][v] = sum_t kb[ns][t+l][v]
__global__ __launch_bounds__(256)
void k3b_kbsum(const float* __restrict__ kb, float* __restrict__ kbsum) {
    int ns = blockIdx.x;
    int idx = threadIdx.x;
    if (idx < NL * VK_) {
        int l = idx / VK_, v = idx % VK_;
        float a = 0.f;
        for (int tt = 0; tt < Tq_; ++tt) a += kb[((size_t)ns * T_ + tt + l) * VK_ + v];
        kbsum[(ns * NL + l) * VK_ + v] = a;
    }
}

// ---------------------------------------------------------------- K4: reduce slices + combine lags + softmax
__global__ __launch_bounds__(256)
void k4_softmax(const float* __restrict__ partial, const float* __restrict__ kbsum,
                bf16* __restrict__ att) {
    int ug = blockIdx.x;  // 0..5 (15 u each)
    int ns = blockIdx.y;
    int u0 = ug * 15;
    __shared__ float sred[NL * 15 * VK_]; // 15 KB
    for (int idx = threadIdx.x; idx < NL * 15 * VK_; idx += 256) {
        int l = idx / (15 * VK_), r = idx % (15 * VK_);
        int u = r / VK_, v = r % VK_;
        const float* p = partial + (((size_t)(ns * NL + l) * 90 + u0 + u) * NSL) * VK_ + v;
        float a = 0.f;
#pragma unroll
        for (int sl = 0; sl < NSL; ++sl) a += p[sl * VK_];
        sred[idx] = a;
    }
    __syncthreads();
    if (threadIdx.x < 15) {
        int u = threadIdx.x;
        const float inv_scale = rsqrtf((float)(C_ * Tq_));
        float pv[VK_];
        float pmax = -1e30f;
#pragma unroll
        for (int v = 0; v < VK_; ++v) {
            float mx = -1e30f, mn = 0.f;
#pragma unroll
            for (int l = 0; l < NL; ++l) {
                float sl = (sred[(l * 15 + u) * VK_ + v] + kbsum[(ns * NL + l) * VK_ + v]) * inv_scale;
                mx = fmaxf(mx, sl); mn += sl;
            }
            pv[v] = 0.5f * (mx + mn * (1.f / NL));
            pmax = fmaxf(pmax, pv[v]);
        }
        float sum = 0.f;
#pragma unroll
        for (int v = 0; v < VK_; ++v) { pv[v] = __expf(pv[v] - pmax); sum += pv[v]; }
        float inv = 1.f / sum;
#pragma unroll
        for (int v = 0; v < VK_; ++v)
            att[((size_t)ns * VQ_ + u0 + u) * VK_ + v] = f2b(pv[v] * inv);
    }
}

// ---------------------------------------------------------------- K5: wv_pack[n][t][g26][o64][j8] = Wos (.) x_v, k = s*50+v
__global__ __launch_bounds__(256)
void k5_wv(const float* __restrict__ x_v, const bf16* __restrict__ WosTb,
           short* __restrict__ wv_pack) {
    int t = blockIdx.x, n = blockIdx.y;
    __shared__ float xv_s[C_ * VK_];               // 12.8 KB
    __shared__ bf16  wos_s[C_ * 256];              // 32 KB, [cj][p]
    __shared__ __align__(16) short kst[KG * KSTR]; // 27 KB
    for (int idx = threadIdx.x; idx < C_ * VK_; idx += 256) {
        int cj = idx / VK_, v = idx % VK_;
        xv_s[idx] = x_v[((size_t)(n * C_ + cj) * T_ + t) * VK_ + v];
    }
    for (int idx = threadIdx.x; idx < C_ * 256; idx += 256)
        wos_s[idx] = WosTb[idx];
    for (int idx = threadIdx.x; idx < KSTR; idx += 256)
        kst[25 * KSTR + idx] = 0;  // zero pad group (k=200..207)
    __syncthreads();
    int p = threadIdx.x, o = p >> 2, s = p & 3;
    float acc[VK_];
#pragma unroll
    for (int v = 0; v < VK_; ++v) acc[v] = 0.f;
    for (int cj = 0; cj < C_; ++cj) {
        float w = b2f(wos_s[cj * 256 + p]);
#pragma unroll
        for (int v = 0; v < VK_; ++v) acc[v] += w * xv_s[cj * VK_ + v];
    }
#pragma unroll
    for (int v = 0; v < VK_; ++v) {
        int k = s * VK_ + v;
        kst[(k >> 3) * KSTR + o * 8 + (k & 7)] = f2bs(acc[v]);
    }
    __syncthreads();
    short* dst = wv_pack + (size_t)(n * T_ + t) * (KG * 512);
    for (int m = threadIdx.x; m < KG * 64; m += 256) {
        int g = m >> 6, o2 = m & 63;
        *(short8*)(dst + m * 8) = *(const short8*)(kst + g * KSTR + o2 * 8);
    }
}

// ---------------------------------------------------------------- K6: MFMA y-path
// out_pre[n][o][t][u] = bos[o] + sum_k wv_pack[n][t][k][o] * att[n][k][u]
// M=o (2x32), N=u (3x32, pad 96), K=208. A from global (coalesced), B from LDS.
__global__ __launch_bounds__(256)
void k6_mfma(const bf16* __restrict__ att, const short* __restrict__ wv_pack,
             const float* __restrict__ bos, bf16* __restrict__ out_pre) {
    int tc = blockIdx.x, n = blockIdx.y;
    __shared__ __align__(16) short att_p[KG * 96 * 8]; // 39936 B
    __shared__ float bos_s[64];
    int tid = threadIdx.x;
    if (tid < 64) bos_s[tid] = bos[tid];
    for (int m = tid; m < 96 * 208; m += 256) {
        int u = m / 208, k = m - u * 208;
        short val = 0;
        if (u < 90 && k < 200) {
            int s = k / VK_, v = k - s * VK_;
            bf16 h = att[((size_t)(n * 4 + s) * 90 + u) * VK_ + v];
            val = *reinterpret_cast<short*>(&h);
        }
        att_p[((k >> 3) * 96 + u) * 8 + (k & 7)] = val;
    }
    __syncthreads();
    int wave = tid >> 6, lane = tid & 63;
    int q = lane >> 5, c = lane & 31;
    int t = tc * 4 + wave;
    f32x16 acc[6];
#pragma unroll
    for (int ot = 0; ot < 2; ++ot)
#pragma unroll
        for (int r = 0; r < 16; ++r) {
            float b = bos_s[ot * 32 + (r & 3) + 8 * (r >> 2) + 4 * q];
            acc[ot * 3 + 0][r] = b; acc[ot * 3 + 1][r] = b; acc[ot * 3 + 2][r] = b;
        }
    const short* wbase = wv_pack + (size_t)(n * T_ + t) * (KG * 512);
#pragma unroll
    for (int st = 0; st < 13; ++st) {
        int gq = 2 * st + q;
        short8 a0 = *(const short8*)(wbase + (gq * 64 + c) * 8);
        short8 a1 = *(const short8*)(wbase + (gq * 64 + 32 + c) * 8);
        short8 b0 = *(const short8*)(att_p + (gq * 96 + c) * 8);
        short8 b1 = *(const short8*)(att_p + (gq * 96 + 32 + c) * 8);
        short8 b2 = *(const short8*)(att_p + (gq * 96 + 64 + c) * 8);
        acc[0] = __builtin_amdgcn_mfma_f32_32x32x16_bf16(a0, b0, acc[0], 0, 0, 0);
        acc[1] = __builtin_amdgcn_mfma_f32_32x32x16_bf16(a0, b1, acc[1], 0, 0, 0);
        acc[2] = __builtin_amdgcn_mfma_f32_32x32x16_bf16(a0, b2, acc[2], 0, 0, 0);
        acc[3] = __builtin_amdgcn_mfma_f32_32x32x16_bf16(a1, b0, acc[3], 0, 0, 0);
        acc[4] = __builtin_amdgcn_mfma_f32_32x32x16_bf16(a1, b1, acc[4], 0, 0, 0);
        acc[5] = __builtin_amdgcn_mfma_f32_32x32x16_bf16(a1, b2, acc[5], 0, 0, 0);
    }
#pragma unroll
    for (int ot = 0; ot < 2; ++ot)
#pragma unroll
        for (int ut = 0; ut < 3; ++ut) {
            int u = ut * 32 + c;
            if (u < 90) {
                f32x16 A = acc[ot * 3 + ut];
#pragma unroll
                for (int r = 0; r < 16; ++r) {
                    int o = ot * 32 + (r & 3) + 8 * (r >> 2) + 4 * q;
                    out_pre[((size_t)(n * 64 + o) * 256 + t) * 90 + u] = f2b(A[r]);
                }
            }
        }
}

// ---------------------------------------------------------------- K7: down conv (KR=64)
__global__ __launch_bounds__(256)
void k7_down(const float* __restrict__ X, const float* __restrict__ W,
             const float* __restrict__ bias, bf16* __restrict__ out) {
    int n = blockIdx.y;
    int col0 = blockIdx.x * 128;
    __shared__ float w_s[64 * 65];
    __shared__ float x_s[64 * 128];
    int to = threadIdx.x >> 5, tcol = threadIdx.x & 31;
    float acc[8][4] = {};
    for (int idx = threadIdx.x; idx < 64 * 64; idx += 256) {
        int o = idx >> 6, k = idx & 63;
        w_s[k * 65 + o] = W[o * C_ + k];
    }
    for (int idx = threadIdx.x; idx < 64 * 128; idx += 256) {
        int k = idx >> 7, c = idx & 127;
        x_s[k * 128 + c] = X[((size_t)n * C_ + k) * COLS + col0 + c];
    }
    __syncthreads();
#pragma unroll 4
    for (int k = 0; k < 64; ++k) {
        float wvr[8], xvr[4];
#pragma unroll
        for (int i = 0; i < 8; ++i) wvr[i] = w_s[k * 65 + to * 8 + i];
#pragma unroll
        for (int j = 0; j < 4; ++j) xvr[j] = x_s[k * 128 + tcol + 32 * j];
#pragma unroll
        for (int i = 0; i < 8; ++i)
#pragma unroll
            for (int j = 0; j < 4; ++j) acc[i][j] += wvr[i] * xvr[j];
    }
#pragma unroll
    for (int i = 0; i < 8; ++i) {
        int o = to * 8 + i;
        float b = bias[o];
#pragma unroll
        for (int j = 0; j < 4; ++j)
            out[((size_t)n * C_ + o) * COLS + col0 + tcol + 32 * j] = f2b(acc[i][j] + b);
    }
}

// ---------------------------------------------------------------- K8: per-channel sum/sumsq
__global__ __launch_bounds__(256)
void k8_stats(const bf16* __restrict__ out_pre, const bf16* __restrict__ d_pre,
              float* __restrict__ stats) {
    int path = blockIdx.x >> 9;
    int b = blockIdx.x & 511;
    int o = b >> 3, n = b & 7;
    const bf16* p = (path ? d_pre : out_pre) + ((size_t)n * C_ + o) * COLS;
    float s = 0.f, sq = 0.f;
    for (int i = threadIdx.x; i < COLS; i += 256) {
        float x = b2f(p[i]);
        s += x; sq += x * x;
    }
#pragma unroll
    for (int off = 32; off > 0; off >>= 1) {
        s  += __shfl_down(s, off, 64);
        sq += __shfl_down(sq, off, 64);
    }
    __shared__ float red[8];
    int wid = threadIdx.x >> 6, lane = threadIdx.x & 63;
    if (lane == 0) { red[wid * 2] = s; red[wid * 2 + 1] = sq; }
    __syncthreads();
    if (threadIdx.x == 0) {
        float S = 0.f, Q = 0.f;
        for (int w2 = 0; w2 < 4; ++w2) { S += red[w2 * 2]; Q += red[w2 * 2 + 1]; }
        atomicAdd(&stats[path * 128 + o * 2], S);
        atomicAdd(&stats[path * 128 + o * 2 + 1], Q);
    }
}

// ---------------------------------------------------------------- K9: BN + BN + add + leaky relu (fp32 out)
__global__ __launch_bounds__(256)
void k9_final(const bf16* __restrict__ out_pre, const bf16* __restrict__ d_pre,
              const float* __restrict__ stats,
              const float* __restrict__ gamma_out, const float* __restrict__ beta_out,
              const float* __restrict__ gamma_down, const float* __restrict__ beta_down,
              float* __restrict__ out) {
    const float invM = 1.f / ((float)N_ * COLS);
    size_t total = (size_t)N_ * C_ * COLS;
    size_t stride = (size_t)gridDim.x * blockDim.x;
    for (size_t idx = (size_t)blockIdx.x * blockDim.x + threadIdx.x; idx < total; idx += stride) {
        int o = (int)((idx / COLS) % C_);
        float my = stats[o * 2] * invM;
        float vy = stats[o * 2 + 1] * invM - my * my;
        float md = stats[128 + o * 2] * invM;
        float vd = stats[128 + o * 2 + 1] * invM - md * md;
        float yn = (b2f(out_pre[idx]) - my) * rsqrtf(vy + EPSf) * gamma_out[o] + beta_out[o];
        float dn = (b2f(d_pre[idx]) - md) * rsqrtf(vd + EPSf) * gamma_down[o] + beta_down[o];
        float r = yn + dn;
        out[idx] = r > 0.f ? r : 0.1f * r;
    }
}

// ----------------------------------------------------------------
extern "C" void kernel_launch(void* const* d_in, const int* in_sizes, int n_in,
                              void* d_out, int out_size, void* d_ws, size_t ws_size,
                              hipStream_t stream) {
    (void)in_sizes; (void)n_in; (void)out_size; (void)ws_size;
    const float* x_q  = (const float*)d_in[0];
    const float* x_k  = (const float*)d_in[1];
    const float* x_v  = (const float*)d_in[2];
    const float* Wq   = (const float*)d_in[3];
    const float* bq   = (const float*)d_in[4];
    const float* Wk   = (const float*)d_in[5];
    const float* bk   = (const float*)d_in[6];
    const float* Wv   = (const float*)d_in[7];
    const float* bv   = (const float*)d_in[8];
    const float* Wout = (const float*)d_in[9];
    const float* bout = (const float*)d_in[10];
    const float* gamma_out  = (const float*)d_in[11];
    const float* beta_out   = (const float*)d_in[12];
    const float* Wdown = (const float*)d_in[13];
    const float* bdown = (const float*)d_in[14];
    const float* gamma_down = (const float*)d_in[15];
    const float* beta_down  = (const float*)d_in[16];

    char* w = (char*)d_ws;
    size_t off = 0;
    auto nxt = [&](size_t bytes) {
        char* p = w + off;
        off += (bytes + 255) & ~(size_t)255;
        return p;
    };
    float* Mt      = (float*)nxt((size_t)S_ * C_ * C_ * 4);
    float* bM      = (float*)nxt((size_t)S_ * C_ * 4);
    float* wbp     = (float*)nxt((size_t)S_ * C_ * 4);
    float* cbp     = (float*)nxt((size_t)S_ * 4);
    bf16*  WosTb   = (bf16*)nxt((size_t)C_ * 256 * 2);
    float* bos     = (float*)nxt((size_t)C_ * 4);
    short* xqT     = (short*)nxt((size_t)N_ * 8 * T_ * 96 * 8 * 2);       // 25.2 MB
    short* kqT     = (short*)nxt((size_t)N_ * S_ * 8 * T_ * VK_ * 8 * 2); // 52.4 MB
    float* kb      = (float*)nxt((size_t)N_ * S_ * T_ * VK_ * 4);         // 6.6 MB
    float* kbsum   = (float*)nxt((size_t)N_ * S_ * NL * VK_ * 4);
    float* partial = (float*)nxt((size_t)N_ * S_ * NL * 90 * NSL * VK_ * 4); // 46 MB
    bf16*  att     = (bf16*)nxt((size_t)N_ * S_ * VQ_ * VK_ * 2);
    short* wv_pack = (short*)nxt((size_t)N_ * T_ * KG * 512 * 2);         // 54.5 MB
    bf16*  out_pre = (bf16*)nxt((size_t)N_ * C_ * T_ * VQ_ * 2);          // 23.6 MB
    bf16*  d_pre   = (bf16*)nxt((size_t)N_ * C_ * T_ * VQ_ * 2);          // 23.6 MB
    float* stats   = (float*)nxt(256 * 4);

    hipMemsetAsync(stats, 0, 256 * 4, stream);

    k0_precompute<<<S_ * C_, 64, 0, stream>>>(Wq, bq, Wk, bk, Mt, bM, wbp, cbp);
    k0b_wos<<<C_, 256, 0, stream>>>(Wout, bout, Wv, bv, WosTb, bos);
    k0c_xqt<<<dim3(T_, N_), 128, 0, stream>>>(x_q, xqT);
    k1_kq<<<N_ * T_, 256, 0, stream>>>(x_k, Mt, bM, wbp, cbp, kqT, kb);
    k3b_kbsum<<<N_ * S_, 256, 0, stream>>>(kb, kbsum);
    k3_mfma<<<dim3(NSL, N_ * S_), 256, 0, stream>>>(xqT, kqT, partial);
    k4_softmax<<<dim3(6, N_ * S_), 256, 0, stream>>>(partial, kbsum, att);
    k5_wv<<<dim3(T_, N_), 256, 0, stream>>>(x_v, WosTb, wv_pack);
    k6_mfma<<<dim3(T_ / 4, N_), 256, 0, stream>>>(att, wv_pack, bos, out_pre);
    k7_down<<<dim3(COLS / 128, N_), 256, 0, stream>>>(x_q, Wdown, bdown, d_pre);
    k8_stats<<<1024, 256, 0, stream>>>(out_pre, d_pre, stats);
    k9_final<<<8192, 256, 0, stream>>>(out_pre, d_pre, stats, gamma_out, beta_out,
                                       gamma_down, beta_down, (float*)d_out);
}

// Round 5
// 454.658 us; speedup vs baseline: 2.6658x; 1.2659x over previous
//
#include <hip/hip_runtime.h>
#include <hip/hip_bf16.h>

typedef __hip_bfloat16 bf16;
typedef __attribute__((ext_vector_type(8))) short short8;
typedef __attribute__((ext_vector_type(16))) float f32x16;

__device__ __forceinline__ float b2f(bf16 x) { return __bfloat162float(x); }
__device__ __forceinline__ bf16  f2b(float x) { return __float2bfloat16(x); }
__device__ __forceinline__ short f2bs(float x) {
    bf16 h = __float2bfloat16(x);
    return *reinterpret_cast<short*>(&h);
}

constexpr int N_ = 8, C_ = 64, T_ = 256, VQ_ = 90, VK_ = 50, S_ = 4, L_ = 4;
constexpr int Tq_ = T_ - L_;     // 252
constexpr int NL  = L_ + 1;      // 5 lags
constexpr int COLS = T_ * VQ_;   // 23040
constexpr float EPSf = 1e-5f;
constexpr int NSL = 16;          // score partial K-slices

// Shared-memory pool for the M=256/K=64 GEMM template (k1, k5)
union SMemG {
    struct { short A[8 * 256 * 8]; short B[8 * 128 * 8]; } ab; // 32KB + 16KB
    short buf[4][64 * 66];                                     // 33.8KB epilogue
};

// ---------------------------------------------------------------- K0: fold Wq into key side
// MtA[kg][p=s*64+ci][j8] bf16 : A-operand for k1.  bMp[p] fp32 bias.
__global__ __launch_bounds__(64)
void k0_precompute(const float* __restrict__ Wq, const float* __restrict__ bq,
                   const float* __restrict__ Wk, const float* __restrict__ bk,
                   short* __restrict__ MtA, float* __restrict__ bMp,
                   float* __restrict__ wb, float* __restrict__ cb) {
    int s  = blockIdx.x >> 6;
    int ci = blockIdx.x & 63;
    int cj = threadIdx.x;
    float m = 0.f;
    for (int c = 0; c < C_; ++c)
        m += Wq[(s * C_ + c) * C_ + ci] * Wk[(s * C_ + c) * C_ + cj];
    MtA[((cj >> 3) * 256 + s * C_ + ci) * 8 + (cj & 7)] = f2bs(m);
    if (cj == 0) {
        float v = 0.f;
        for (int c = 0; c < C_; ++c)
            v += Wq[(s * C_ + c) * C_ + ci] * bk[s * C_ + c];
        bMp[s * C_ + ci] = v;
    }
    if (ci == 0) {
        float v = 0.f;
        for (int c = 0; c < C_; ++c)
            v += bq[s * C_ + c] * Wk[(s * C_ + c) * C_ + cj];
        wb[s * C_ + cj] = v;
        if (cj == 0) {
            float v2 = 0.f;
            for (int c = 0; c < C_; ++c)
                v2 += bq[s * C_ + c] * bk[s * C_ + c];
            cb[s] = v2;
        }
    }
}

// ---------------------------------------------------------------- K0b: fold Wout into Wv
// WosA[kg][p=s*64+o][j8] bf16 ; bos[o]
__global__ __launch_bounds__(256)
void k0b_wos(const float* __restrict__ Wout, const float* __restrict__ bout,
             const float* __restrict__ Wv, const float* __restrict__ bv,
             short* __restrict__ WosA, float* __restrict__ bos) {
    int cj = blockIdx.x;
    __shared__ float wvcol[C_];
    if (threadIdx.x < C_) wvcol[threadIdx.x] = Wv[threadIdx.x * C_ + cj];
    __syncthreads();
    int p = threadIdx.x;       // p = s*64 + o
    int s = p >> 6, o = p & 63;
    float acc = 0.f;
    for (int c = 0; c < C_; ++c)
        acc += Wout[o * (S_ * C_) + s * C_ + c] * wvcol[c];
    WosA[((cj >> 3) * 256 + p) * 8 + (cj & 7)] = f2bs(acc);
    if (cj == 0 && p < C_) {
        float a = bout[p];
        for (int k = 0; k < S_ * C_; ++k)
            a += Wout[p * (S_ * C_) + k] * bv[k & 63];
        bos[p] = a;
    }
}

// ---------------------------------------------------------------- K0c: xqT[n][g][t][u96][cc8] bf16
__global__ __launch_bounds__(128)
void k0c_xqt(const float* __restrict__ xq, short* __restrict__ xqT) {
    int t = blockIdx.x, n = blockIdx.y;
    int u = threadIdx.x;
    if (u >= 96) return;
    for (int g = 0; g < 8; ++g) {
        short8 pack;
#pragma unroll
        for (int j = 0; j < 8; ++j) {
            float val = (u < 90) ? xq[((size_t)(n * 64 + g * 8 + j) * 256 + t) * 90 + u] : 0.f;
            pack[j] = f2bs(val);
        }
        *(short8*)(xqT + ((size_t)((n * 8 + g) * 256 + t) * 96 + u) * 8) = pack;
    }
}

// ---------------------------------------------------------------- K1: MFMA kq = Mt @ x_k + bM -> kqT[ns][g][t][v][cc8]
// M=p=(s,ci)=256, N=(t,v) 2 t per block (64-padded cols), K=cj=64
__global__ __launch_bounds__(256)
void k1_mfma(const float* __restrict__ x_k, const short* __restrict__ MtA,
             const float* __restrict__ bMp, short* __restrict__ kqT) {
    int tb = blockIdx.x, n = blockIdx.y;
    int t0 = tb * 2;
    __shared__ SMemG u;
    __shared__ float bmp_s[256];
    int tid = threadIdx.x;
    if (tid < 256) bmp_s[tid] = bMp[tid];
    for (int i = tid; i < 2048; i += 256)
        ((short8*)u.ab.A)[i] = ((const short8*)MtA)[i];
    for (int m = tid; m < 8 * 128; m += 256) {
        int kg = m >> 7, c = m & 127;
        int t = c >> 6, v = c & 63;
        short8 pk;
        if (v < VK_) {
            const float* src = x_k + ((size_t)(n * 64 + kg * 8) * 256 + t0 + t) * VK_ + v;
#pragma unroll
            for (int j = 0; j < 8; ++j) pk[j] = f2bs(src[(size_t)j * 256 * VK_]);
        } else {
#pragma unroll
            for (int j = 0; j < 8; ++j) pk[j] = 0;
        }
        *(short8*)(u.ab.B + m * 8) = pk;
    }
    __syncthreads();
    int wave = tid >> 6, lane = tid & 63, q = lane >> 5, c32 = lane & 31;
    f32x16 acc[2][4];
#pragma unroll
    for (int mt = 0; mt < 2; ++mt) {
#pragma unroll
        for (int r = 0; r < 16; ++r) {
            float b = bmp_s[wave * 64 + mt * 32 + (r & 3) + 8 * (r >> 2) + 4 * q];
#pragma unroll
            for (int nt = 0; nt < 4; ++nt) acc[mt][nt][r] = b;
        }
    }
#pragma unroll
    for (int ks = 0; ks < 4; ++ks) {
        int kg = 2 * ks + q;
        short8 a0 = *(const short8*)(u.ab.A + (kg * 256 + wave * 64 + c32) * 8);
        short8 a1 = *(const short8*)(u.ab.A + (kg * 256 + wave * 64 + 32 + c32) * 8);
#pragma unroll
        for (int nt = 0; nt < 4; ++nt) {
            short8 b = *(const short8*)(u.ab.B + (kg * 128 + nt * 32 + c32) * 8);
            acc[0][nt] = __builtin_amdgcn_mfma_f32_32x32x16_bf16(a0, b, acc[0][nt], 0, 0, 0);
            acc[1][nt] = __builtin_amdgcn_mfma_f32_32x32x16_bf16(a1, b, acc[1][nt], 0, 0, 0);
        }
    }
    __syncthreads();  // A/B dead, buf becomes live
    int ns = n * 4 + wave;
    for (int t = 0; t < 2; ++t) {
#pragma unroll
        for (int mt = 0; mt < 2; ++mt)
#pragma unroll
            for (int ntl = 0; ntl < 2; ++ntl) {
                f32x16 A = acc[mt][t * 2 + ntl];
                int cloc = ntl * 32 + c32;
#pragma unroll
                for (int r = 0; r < 16; ++r) {
                    int ci = mt * 32 + (r & 3) + 8 * (r >> 2) + 4 * q;
                    u.buf[wave][cloc * 66 + ci] = f2bs(A[r]);
                }
            }
        __syncthreads();
        if (lane < VK_) {
#pragma unroll
            for (int g = 0; g < 8; ++g) {
                short8 pk;
#pragma unroll
                for (int j = 0; j < 8; ++j) pk[j] = u.buf[wave][lane * 66 + g * 8 + j];
                *(short8*)(kqT + ((((size_t)ns * 8 + g) * 256 + t0 + t) * VK_ + lane) * 8) = pk;
            }
        }
        __syncthreads();
    }
}

// ---------------------------------------------------------------- K3b: kbsum from x_k sliding sums
// kbsum[ns][l][v] = 252*cb[s] + sum_cj wb[s][cj] * sum_{t=l..251+l} x_k[n][cj][t][v]
__global__ __launch_bounds__(128)
void k3b_kbsum(const float* __restrict__ x_k, const float* __restrict__ wb,
               const float* __restrict__ cb, float* __restrict__ kbsum) {
    int cjg = blockIdx.x;  // 32 groups of 2 cj
    int n = blockIdx.y;
    __shared__ float S[2][NL][VK_];
    for (int pr = threadIdx.x; pr < 2 * VK_; pr += 128) {
        int cjl = pr / VK_, v = pr % VK_;
        const float* base = x_k + ((size_t)(n * 64 + cjg * 2 + cjl) * 256) * VK_ + v;
        float a = 0.f;
        for (int t = 0; t < Tq_; ++t) a += base[t * VK_];
        S[cjl][0][v] = a;
        float run = a;
        for (int l = 1; l < NL; ++l) {
            run += base[(251 + l) * VK_] - base[(l - 1) * VK_];
            S[cjl][l][v] = run;
        }
    }
    __syncthreads();
    for (int e = threadIdx.x; e < S_ * NL * VK_; e += 128) {
        int s = e / (NL * VK_), r = e % (NL * VK_), l = r / VK_, v = r % VK_;
        float a = wb[s * 64 + cjg * 2] * S[0][l][v] + wb[s * 64 + cjg * 2 + 1] * S[1][l][v];
        if (cjg == 0) a += (float)Tq_ * cb[s];
        atomicAdd(&kbsum[((size_t)(n * 4 + s) * NL + l) * VK_ + v], a);
    }
}

// ---------------------------------------------------------------- K3: MFMA scores (unchanged)
__global__ __launch_bounds__(256)
void k3_mfma(const short* __restrict__ xqT, const short* __restrict__ kqT,
             float* __restrict__ partial) {
    int gx = blockIdx.x;
    int g = gx >> 1, half = gx & 1;
    int ns = blockIdx.y;
    int n = ns >> 2;
    __shared__ __align__(16) short xa[12 * 96 * 8];
    __shared__ __align__(16) short kbs[16 * VK_ * 8];
    int tid = threadIdx.x;
    int wave = tid >> 6, lane = tid & 63;
    int q = lane >> 5, nl = lane & 31;
    int n1 = wave * 64 + nl, n2 = n1 + 32;
    int nc1 = min(n1, 249), nc2 = min(n2, 249);
    int l1 = nc1 / VK_, v1 = nc1 % VK_;
    int l2 = nc2 / VK_, v2 = nc2 % VK_;
    int bo1 = ((q + l1) * VK_ + v1) * 8;
    int bo2 = ((q + l2) * VK_ + v2) * 8;
    int ao = (q * 96 + nl) * 8;
    f32x16 acc[6];
#pragma unroll
    for (int i = 0; i < 6; ++i)
#pragma unroll
        for (int r = 0; r < 16; ++r) acc[i][r] = 0.f;
    const short* asrc = xqT + (size_t)(n * 8 + g) * 256 * 768;
    const short* bsrc = kqT + (size_t)(ns * 8 + g) * 256 * 400;
    int c0 = half * 10, c1 = half ? 21 : 10;
    for (int ch = c0; ch < c1; ++ch) {
        int t0 = ch * 12;
        __syncthreads();
        {
            const short* as = asrc + t0 * 768;
            for (int i = tid; i < 1152; i += 256)
                *(short8*)(xa + i * 8) = *(const short8*)(as + i * 8);
            const short* bs = bsrc + t0 * 400;
            for (int i = tid; i < 800; i += 256)
                *(short8*)(kbs + i * 8) = *(const short8*)(bs + i * 8);
        }
        __syncthreads();
#pragma unroll
        for (int ts = 0; ts < 6; ++ts) {
            short8 a0 = *(const short8*)(xa + ao + ts * 1536);
            short8 a1 = *(const short8*)(xa + ao + 256 + ts * 1536);
            short8 a2 = *(const short8*)(xa + ao + 512 + ts * 1536);
            short8 b0 = *(const short8*)(kbs + bo1 + ts * 800);
            short8 b1 = *(const short8*)(kbs + bo2 + ts * 800);
            acc[0] = __builtin_amdgcn_mfma_f32_32x32x16_bf16(a0, b0, acc[0], 0, 0, 0);
            acc[1] = __builtin_amdgcn_mfma_f32_32x32x16_bf16(a1, b0, acc[1], 0, 0, 0);
            acc[2] = __builtin_amdgcn_mfma_f32_32x32x16_bf16(a2, b0, acc[2], 0, 0, 0);
            acc[3] = __builtin_amdgcn_mfma_f32_32x32x16_bf16(a0, b1, acc[3], 0, 0, 0);
            acc[4] = __builtin_amdgcn_mfma_f32_32x32x16_bf16(a1, b1, acc[4], 0, 0, 0);
            acc[5] = __builtin_amdgcn_mfma_f32_32x32x16_bf16(a2, b1, acc[5], 0, 0, 0);
        }
    }
#pragma unroll
    for (int inb = 0; inb < 2; ++inb) {
        int ng = wave * 64 + inb * 32 + nl;
        if (ng < 250) {
            int l = ng / VK_, v = ng % VK_;
            float* pb = partial + ((((size_t)ns * 5 + l) * 90) * NSL + gx) * VK_ + v;
#pragma unroll
            for (int iu = 0; iu < 3; ++iu) {
#pragma unroll
                for (int r = 0; r < 16; ++r) {
                    int u2 = iu * 32 + (r & 3) + 8 * (r >> 2) + 4 * q;
                    if (u2 < 90) pb[(size_t)u2 * NSL * VK_] = acc[inb * 3 + iu][r];
                }
            }
        }
    }
}

// ---------------------------------------------------------------- K4: reduce slices + combine lags + softmax
__global__ __launch_bounds__(256)
void k4_softmax(const float* __restrict__ partial, const float* __restrict__ kbsum,
                bf16* __restrict__ att) {
    int ug = blockIdx.x;
    int ns = blockIdx.y;
    int u0 = ug * 15;
    __shared__ float sred[NL * 15 * VK_];
    for (int idx = threadIdx.x; idx < NL * 15 * VK_; idx += 256) {
        int l = idx / (15 * VK_), r = idx % (15 * VK_);
        int u2 = r / VK_, v = r % VK_;
        const float* p = partial + (((size_t)(ns * NL + l) * 90 + u0 + u2) * NSL) * VK_ + v;
        float a = 0.f;
#pragma unroll
        for (int sl = 0; sl < NSL; ++sl) a += p[sl * VK_];
        sred[idx] = a;
    }
    __syncthreads();
    if (threadIdx.x < 15) {
        int u2 = threadIdx.x;
        const float inv_scale = rsqrtf((float)(C_ * Tq_));
        float pv[VK_];
        float pmax = -1e30f;
#pragma unroll
        for (int v = 0; v < VK_; ++v) {
            float mx = -1e30f, mn = 0.f;
#pragma unroll
            for (int l = 0; l < NL; ++l) {
                float sl = (sred[(l * 15 + u2) * VK_ + v] + kbsum[((size_t)ns * NL + l) * VK_ + v]) * inv_scale;
                mx = fmaxf(mx, sl); mn += sl;
            }
            pv[v] = 0.5f * (mx + mn * (1.f / NL));
            pmax = fmaxf(pmax, pv[v]);
        }
        float sum = 0.f;
#pragma unroll
        for (int v = 0; v < VK_; ++v) { pv[v] = __expf(pv[v] - pmax); sum += pv[v]; }
        float inv = 1.f / sum;
#pragma unroll
        for (int v = 0; v < VK_; ++v)
            att[((size_t)ns * VQ_ + u0 + u2) * VK_ + v] = f2b(pv[v] * inv);
    }
}

// ---------------------------------------------------------------- K5: MFMA wv_pack[n][t][g32][o64][j8]
// M=p=(s,o)=256, N=(t,v) 2 t per block, K=cj=64. k-slot = s*64 + v (v>=50 zero).
__global__ __launch_bounds__(256)
void k5_mfma(const float* __restrict__ x_v, const short* __restrict__ WosA,
             short* __restrict__ wv_pack) {
    int tb = blockIdx.x, n = blockIdx.y;
    int t0 = tb * 2;
    __shared__ SMemG u;
    int tid = threadIdx.x;
    for (int i = tid; i < 2048; i += 256)
        ((short8*)u.ab.A)[i] = ((const short8*)WosA)[i];
    for (int m = tid; m < 8 * 128; m += 256) {
        int kg = m >> 7, c = m & 127;
        int t = c >> 6, v = c & 63;
        short8 pk;
        if (v < VK_) {
            const float* src = x_v + ((size_t)(n * 64 + kg * 8) * 256 + t0 + t) * VK_ + v;
#pragma unroll
            for (int j = 0; j < 8; ++j) pk[j] = f2bs(src[(size_t)j * 256 * VK_]);
        } else {
#pragma unroll
            for (int j = 0; j < 8; ++j) pk[j] = 0;
        }
        *(short8*)(u.ab.B + m * 8) = pk;
    }
    __syncthreads();
    int wave = tid >> 6, lane = tid & 63, q = lane >> 5, c32 = lane & 31;
    f32x16 acc[2][4];
#pragma unroll
    for (int mt = 0; mt < 2; ++mt)
#pragma unroll
        for (int nt = 0; nt < 4; ++nt)
#pragma unroll
            for (int r = 0; r < 16; ++r) acc[mt][nt][r] = 0.f;
#pragma unroll
    for (int ks = 0; ks < 4; ++ks) {
        int kg = 2 * ks + q;
        short8 a0 = *(const short8*)(u.ab.A + (kg * 256 + wave * 64 + c32) * 8);
        short8 a1 = *(const short8*)(u.ab.A + (kg * 256 + wave * 64 + 32 + c32) * 8);
#pragma unroll
        for (int nt = 0; nt < 4; ++nt) {
            short8 b = *(const short8*)(u.ab.B + (kg * 128 + nt * 32 + c32) * 8);
            acc[0][nt] = __builtin_amdgcn_mfma_f32_32x32x16_bf16(a0, b, acc[0][nt], 0, 0, 0);
            acc[1][nt] = __builtin_amdgcn_mfma_f32_32x32x16_bf16(a1, b, acc[1][nt], 0, 0, 0);
        }
    }
    __syncthreads();
    for (int t = 0; t < 2; ++t) {
#pragma unroll
        for (int mt = 0; mt < 2; ++mt)
#pragma unroll
            for (int ntl = 0; ntl < 2; ++ntl) {
                f32x16 A = acc[mt][t * 2 + ntl];
                int cloc = ntl * 32 + c32;
#pragma unroll
                for (int r = 0; r < 16; ++r) {
                    int o = mt * 32 + (r & 3) + 8 * (r >> 2) + 4 * q;
                    u.buf[wave][cloc * 66 + o] = f2bs(A[r]);
                }
            }
        __syncthreads();
        short* dst = wv_pack + (((size_t)(n * 256 + t0 + t)) * 32 + wave * 8) * 512;
#pragma unroll
        for (int vg = 0; vg < 8; ++vg) {
            short8 pk;
#pragma unroll
            for (int j = 0; j < 8; ++j) pk[j] = u.buf[wave][(vg * 8 + j) * 66 + lane];
            *(short8*)(dst + (size_t)vg * 512 + lane * 8) = pk;
        }
        __syncthreads();
    }
}

// ---------------------------------------------------------------- K6: MFMA y-path, K=256 (4s x 64 v-slots)
__global__ __launch_bounds__(256)
void k6_mfma(const bf16* __restrict__ att, const short* __restrict__ wv_pack,
             const float* __restrict__ bos, bf16* __restrict__ out_pre) {
    int tc = blockIdx.x, n = blockIdx.y;
    __shared__ __align__(16) short att_p[32 * 96 * 8]; // 48KB [g][u][j8]
    __shared__ float bos_s[64];
    int tid = threadIdx.x;
    if (tid < 64) bos_s[tid] = bos[tid];
    for (int m = tid; m < 96 * 256; m += 256) {
        int u2 = m >> 8, k = m & 255;
        int s = k >> 6, vs = k & 63;
        short val = 0;
        if (u2 < 90 && vs < VK_) {
            bf16 h = att[((size_t)(n * 4 + s) * 90 + u2) * VK_ + vs];
            val = *reinterpret_cast<short*>(&h);
        }
        att_p[((k >> 3) * 96 + u2) * 8 + (k & 7)] = val;
    }
    __syncthreads();
    int wave = tid >> 6, lane = tid & 63;
    int q = lane >> 5, c = lane & 31;
    int t = tc * 4 + wave;
    f32x16 acc[6];
#pragma unroll
    for (int ot = 0; ot < 2; ++ot)
#pragma unroll
        for (int r = 0; r < 16; ++r) {
            float b = bos_s[ot * 32 + (r & 3) + 8 * (r >> 2) + 4 * q];
            acc[ot * 3 + 0][r] = b; acc[ot * 3 + 1][r] = b; acc[ot * 3 + 2][r] = b;
        }
    const short* wbase = wv_pack + (size_t)(n * 256 + t) * (32 * 512);
#pragma unroll
    for (int st = 0; st < 16; ++st) {
        int gq = 2 * st + q;
        short8 a0 = *(const short8*)(wbase + (gq * 64 + c) * 8);
        short8 a1 = *(const short8*)(wbase + (gq * 64 + 32 + c) * 8);
        short8 b0 = *(const short8*)(att_p + (gq * 96 + c) * 8);
        short8 b1 = *(const short8*)(att_p + (gq * 96 + 32 + c) * 8);
        short8 b2 = *(const short8*)(att_p + (gq * 96 + 64 + c) * 8);
        acc[0] = __builtin_amdgcn_mfma_f32_32x32x16_bf16(a0, b0, acc[0], 0, 0, 0);
        acc[1] = __builtin_amdgcn_mfma_f32_32x32x16_bf16(a0, b1, acc[1], 0, 0, 0);
        acc[2] = __builtin_amdgcn_mfma_f32_32x32x16_bf16(a0, b2, acc[2], 0, 0, 0);
        acc[3] = __builtin_amdgcn_mfma_f32_32x32x16_bf16(a1, b0, acc[3], 0, 0, 0);
        acc[4] = __builtin_amdgcn_mfma_f32_32x32x16_bf16(a1, b1, acc[4], 0, 0, 0);
        acc[5] = __builtin_amdgcn_mfma_f32_32x32x16_bf16(a1, b2, acc[5], 0, 0, 0);
    }
#pragma unroll
    for (int ot = 0; ot < 2; ++ot)
#pragma unroll
        for (int ut = 0; ut < 3; ++ut) {
            int u2 = ut * 32 + c;
            if (u2 < 90) {
                f32x16 A = acc[ot * 3 + ut];
#pragma unroll
                for (int r = 0; r < 16; ++r) {
                    int o = ot * 32 + (r & 3) + 8 * (r >> 2) + 4 * q;
                    out_pre[((size_t)(n * 64 + o) * 256 + t) * 90 + u2] = f2b(A[r]);
                }
            }
        }
}

// ---------------------------------------------------------------- K7: MFMA down conv
__global__ __launch_bounds__(256)
void k7_mfma(const float* __restrict__ X, const float* __restrict__ W,
             const float* __restrict__ bias, bf16* __restrict__ out) {
    int cb = blockIdx.x, n = blockIdx.y;
    int col0 = cb * 256;
    __shared__ __align__(16) short A[8 * 64 * 8];  // 8KB
    __shared__ __align__(16) short B[8 * 256 * 8]; // 32KB
    __shared__ float bias_s[64];
    int tid = threadIdx.x;
    if (tid < 64) bias_s[tid] = bias[tid];
    for (int idx = tid; idx < 4096; idx += 256) {
        int o = idx >> 6, k = idx & 63;
        A[((k >> 3) * 64 + o) * 8 + (k & 7)] = f2bs(W[o * 64 + k]);
    }
    for (int m = tid; m < 8 * 256; m += 256) {
        int kg = m >> 8, c = m & 255;
        const float* src = X + (size_t)(n * 64 + kg * 8) * COLS + col0 + c;
        short8 pk;
#pragma unroll
        for (int j = 0; j < 8; ++j) pk[j] = f2bs(src[(size_t)j * COLS]);
        *(short8*)(B + m * 8) = pk;
    }
    __syncthreads();
    int wave = tid >> 6, lane = tid & 63, q = lane >> 5, c32 = lane & 31;
    f32x16 acc[2][2];
#pragma unroll
    for (int mt = 0; mt < 2; ++mt)
#pragma unroll
        for (int r = 0; r < 16; ++r) {
            float b = bias_s[mt * 32 + (r & 3) + 8 * (r >> 2) + 4 * q];
            acc[mt][0][r] = b; acc[mt][1][r] = b;
        }
#pragma unroll
    for (int ks = 0; ks < 4; ++ks) {
        int kg = 2 * ks + q;
        short8 a0 = *(const short8*)(A + (kg * 64 + c32) * 8);
        short8 a1 = *(const short8*)(A + (kg * 64 + 32 + c32) * 8);
#pragma unroll
        for (int i = 0; i < 2; ++i) {
            short8 b = *(const short8*)(B + (kg * 256 + (wave * 2 + i) * 32 + c32) * 8);
            acc[0][i] = __builtin_amdgcn_mfma_f32_32x32x16_bf16(a0, b, acc[0][i], 0, 0, 0);
            acc[1][i] = __builtin_amdgcn_mfma_f32_32x32x16_bf16(a1, b, acc[1][i], 0, 0, 0);
        }
    }
#pragma unroll
    for (int mt = 0; mt < 2; ++mt)
#pragma unroll
        for (int i = 0; i < 2; ++i) {
            int col = col0 + (wave * 2 + i) * 32 + c32;
#pragma unroll
            for (int r = 0; r < 16; ++r) {
                int o = mt * 32 + (r & 3) + 8 * (r >> 2) + 4 * q;
                out[(size_t)(n * 64 + o) * COLS + col] = f2b(acc[mt][i][r]);
            }
        }
}

// ---------------------------------------------------------------- K8: per-channel sum/sumsq
__global__ __launch_bounds__(256)
void k8_stats(const bf16* __restrict__ out_pre, const bf16* __restrict__ d_pre,
              float* __restrict__ stats) {
    int path = blockIdx.x >> 9;
    int b = blockIdx.x & 511;
    int o = b >> 3, n = b & 7;
    const bf16* p = (path ? d_pre : out_pre) + ((size_t)n * C_ + o) * COLS;
    float s = 0.f, sq = 0.f;
    for (int i = threadIdx.x; i < COLS; i += 256) {
        float x = b2f(p[i]);
        s += x; sq += x * x;
    }
#pragma unroll
    for (int off = 32; off > 0; off >>= 1) {
        s  += __shfl_down(s, off, 64);
        sq += __shfl_down(sq, off, 64);
    }
    __shared__ float red[8];
    int wid = threadIdx.x >> 6, lane = threadIdx.x & 63;
    if (lane == 0) { red[wid * 2] = s; red[wid * 2 + 1] = sq; }
    __syncthreads();
    if (threadIdx.x == 0) {
        float S = 0.f, Q = 0.f;
        for (int w2 = 0; w2 < 4; ++w2) { S += red[w2 * 2]; Q += red[w2 * 2 + 1]; }
        atomicAdd(&stats[path * 128 + o * 2], S);
        atomicAdd(&stats[path * 128 + o * 2 + 1], Q);
    }
}

// ---------------------------------------------------------------- K9: BN + BN + add + leaky relu (fp32 out)
__global__ __launch_bounds__(256)
void k9_final(const bf16* __restrict__ out_pre, const bf16* __restrict__ d_pre,
              const float* __restrict__ stats,
              const float* __restrict__ gamma_out, const float* __restrict__ beta_out,
              const float* __restrict__ gamma_down, const float* __restrict__ beta_down,
              float* __restrict__ out) {
    const float invM = 1.f / ((float)N_ * COLS);
    size_t total = (size_t)N_ * C_ * COLS;
    size_t stride = (size_t)gridDim.x * blockDim.x;
    for (size_t idx = (size_t)blockIdx.x * blockDim.x + threadIdx.x; idx < total; idx += stride) {
        int o = (int)((idx / COLS) % C_);
        float my = stats[o * 2] * invM;
        float vy = stats[o * 2 + 1] * invM - my * my;
        float md = stats[128 + o * 2] * invM;
        float vd = stats[128 + o * 2 + 1] * invM - md * md;
        float yn = (b2f(out_pre[idx]) - my) * rsqrtf(vy + EPSf) * gamma_out[o] + beta_out[o];
        float dn = (b2f(d_pre[idx]) - md) * rsqrtf(vd + EPSf) * gamma_down[o] + beta_down[o];
        float r = yn + dn;
        out[idx] = r > 0.f ? r : 0.1f * r;
    }
}

// ----------------------------------------------------------------
extern "C" void kernel_launch(void* const* d_in, const int* in_sizes, int n_in,
                              void* d_out, int out_size, void* d_ws, size_t ws_size,
                              hipStream_t stream) {
    (void)in_sizes; (void)n_in; (void)out_size; (void)ws_size;
    const float* x_q  = (const float*)d_in[0];
    const float* x_k  = (const float*)d_in[1];
    const float* x_v  = (const float*)d_in[2];
    const float* Wq   = (const float*)d_in[3];
    const float* bq   = (const float*)d_in[4];
    const float* Wk   = (const float*)d_in[5];
    const float* bk   = (const float*)d_in[6];
    const float* Wv   = (const float*)d_in[7];
    const float* bv   = (const float*)d_in[8];
    const float* Wout = (const float*)d_in[9];
    const float* bout = (const float*)d_in[10];
    const float* gamma_out  = (const float*)d_in[11];
    const float* beta_out   = (const float*)d_in[12];
    const float* Wdown = (const float*)d_in[13];
    const float* bdown = (const float*)d_in[14];
    const float* gamma_down = (const float*)d_in[15];
    const float* beta_down  = (const float*)d_in[16];

    char* w = (char*)d_ws;
    size_t off = 0;
    auto nxt = [&](size_t bytes) {
        char* p = w + off;
        off += (bytes + 255) & ~(size_t)255;
        return p;
    };
    // small persistent buffers
    short* MtA   = (short*)nxt((size_t)8 * 256 * 8 * 2);   // 32KB
    float* bMp   = (float*)nxt(256 * 4);
    float* wbp   = (float*)nxt((size_t)S_ * C_ * 4);
    float* cbp   = (float*)nxt((size_t)S_ * 4);
    short* WosA  = (short*)nxt((size_t)8 * 256 * 8 * 2);   // 32KB
    float* bos   = (float*)nxt((size_t)C_ * 4);
    float* kbsum = (float*)nxt((size_t)N_ * S_ * NL * VK_ * 4); // 32KB
    bf16*  att   = (bf16*)nxt((size_t)N_ * S_ * VQ_ * VK_ * 2);
    float* stats = (float*)nxt(256 * 4);
    // regionA: xqT (k0c->k3) then out_pre (k6->k8,k9)
    char* regionA = nxt((size_t)N_ * 8 * T_ * 96 * 8 * 2);            // 25.2MB
    short* xqT    = (short*)regionA;
    bf16*  out_pre = (bf16*)regionA;
    // regionB: kqT (k1->k3) then d_pre (k7->k8,k9)
    char* regionB = nxt((size_t)N_ * S_ * 8 * T_ * VK_ * 8 * 2);      // 52.4MB
    short* kqT   = (short*)regionB;
    bf16*  d_pre = (bf16*)regionB;
    // regionC: partial (k3->k4) then wv_pack (k5->k6)
    char* regionC = nxt((size_t)N_ * T_ * 32 * 512 * 2);              // 67.1MB
    float* partial = (float*)regionC;
    short* wv_pack = (short*)regionC;

    hipMemsetAsync(stats, 0, 256 * 4, stream);
    hipMemsetAsync(kbsum, 0, (size_t)N_ * S_ * NL * VK_ * 4, stream);

    k0_precompute<<<S_ * C_, 64, 0, stream>>>(Wq, bq, Wk, bk, MtA, bMp, wbp, cbp);
    k0b_wos<<<C_, 256, 0, stream>>>(Wout, bout, Wv, bv, WosA, bos);
    k0c_xqt<<<dim3(T_, N_), 128, 0, stream>>>(x_q, xqT);
    k1_mfma<<<dim3(128, N_), 256, 0, stream>>>(x_k, MtA, bMp, kqT);
    k3b_kbsum<<<dim3(32, N_), 128, 0, stream>>>(x_k, wbp, cbp, kbsum);
    k3_mfma<<<dim3(NSL, N_ * S_), 256, 0, stream>>>(xqT, kqT, partial);
    k4_softmax<<<dim3(6, N_ * S_), 256, 0, stream>>>(partial, kbsum, att);
    k5_mfma<<<dim3(128, N_), 256, 0, stream>>>(x_v, WosA, wv_pack);
    k6_mfma<<<dim3(T_ / 4, N_), 256, 0, stream>>>(att, wv_pack, bos, out_pre);
    k7_mfma<<<dim3(COLS / 256, N_), 256, 0, stream>>>(x_q, Wdown, bdown, d_pre);
    k8_stats<<<1024, 256, 0, stream>>>(out_pre, d_pre, stats);
    k9_final<<<8192, 256, 0, stream>>>(out_pre, d_pre, stats, gamma_out, beta_out,
                                       gamma_down, beta_down, (float*)d_out);
}